// Round 3
// baseline (2901.046 us; speedup 1.0000x reference)
//
#include <hip/hip_runtime.h>
#include <hip/hip_bf16.h>
#include <cstdint>
#include <cstddef>

#define BATCH 32
#define SEQ   4096
#define NF    512
#define NH    8
#define HD    64

// ---------------------------------------------------------------------------
// Pack W{q,k,v} [H][F][D] -> [F][512] row-major, column n = h*64+d.
// (biases bq/bk/bv are already contiguous [H][64] == [512] flat.)
// ---------------------------------------------------------------------------
__global__ void pack3_kernel(const float* __restrict__ Wq, const float* __restrict__ Wk,
                             const float* __restrict__ Wv,
                             float* __restrict__ Wq_all, float* __restrict__ Wk_all,
                             float* __restrict__ Wv_all) {
  int i = blockIdx.x * 256 + threadIdx.x;     // over 512*512
  if (i >= NF * NF) return;
  int f = i >> 9, n = i & 511, h = n >> 6, d = n & 63;
  size_t src = ((size_t)h * NF + f) * HD + d;
  Wq_all[i] = Wq[src];
  Wk_all[i] = Wk[src];
  Wv_all[i] = Wv[src];
}

// ---------------------------------------------------------------------------
// Partial column sums of x: s_part[b][c][f] = sum over 256 rows of chunk c.
// grid (32, 16), 256 threads.
// ---------------------------------------------------------------------------
__global__ __launch_bounds__(256) void colsum_kernel(const float* __restrict__ x,
                                                     float* __restrict__ s_part) {
  const int b = blockIdx.x, c = blockIdx.y, t = threadIdx.x;
  const float* base = x + ((size_t)b * SEQ + c * 256) * NF;
  float a0 = 0.f, a1 = 0.f;
  for (int l = 0; l < 256; ++l) {
    a0 += base[(size_t)l * NF + t];
    a1 += base[(size_t)l * NF + t + 256];
  }
  float* o = s_part + ((size_t)b * 16 + c) * NF;
  o[t] = a0;
  o[t + 256] = a1;
}

// ---------------------------------------------------------------------------
// Finish colsum; p_q[b] = s[b] @ Wq_all, p_k[b] = s[b] @ Wk_all.
// grid 32, 256 threads.
// ---------------------------------------------------------------------------
__global__ __launch_bounds__(256) void pqk_kernel(
    const float* __restrict__ s_part, const float* __restrict__ Wq_all,
    const float* __restrict__ Wk_all, float* __restrict__ pq, float* __restrict__ pk) {
  const int b = blockIdx.x, t = threadIdx.x;
  __shared__ float s[512];
  float a0 = 0.f, a1 = 0.f;
  for (int c = 0; c < 16; ++c) {
    a0 += s_part[((size_t)b * 16 + c) * NF + t];
    a1 += s_part[((size_t)b * 16 + c) * NF + t + 256];
  }
  s[t] = a0;
  s[t + 256] = a1;
  __syncthreads();
  float q0 = 0.f, q1 = 0.f, k0 = 0.f, k1 = 0.f;
  for (int f = 0; f < NF; ++f) {
    const float sv = s[f];
    q0 += sv * Wq_all[(size_t)f * NF + t];
    q1 += sv * Wq_all[(size_t)f * NF + t + 256];
    k0 += sv * Wk_all[(size_t)f * NF + t];
    k1 += sv * Wk_all[(size_t)f * NF + t + 256];
  }
  pq[(size_t)b * NF + t] = q0;
  pq[(size_t)b * NF + t + 256] = q1;
  pk[(size_t)b * NF + t] = k0;
  pk[(size_t)b * NF + t + 256] = k1;
}

// ---------------------------------------------------------------------------
// Gram: G[b] = x[b]^T x[b], [512x512], K = 4096 (TN gemm, LDS-friendly).
// grid (4, 4, 32), 256 threads, 128x128 tile, BK=16, split-4 microtile.
// ---------------------------------------------------------------------------
__global__ __launch_bounds__(256) void gram_kernel(const float* __restrict__ x,
                                                   float* __restrict__ G) {
  const int b = blockIdx.z;
  const int m0 = blockIdx.y * 128, n0 = blockIdx.x * 128;
  __shared__ float As[16][128];
  __shared__ float Bs[16][128];
  const int tid = threadIdx.x, tx = tid & 15, ty = tid >> 4;
  const float* xb = x + (size_t)b * SEQ * NF;
  const int fl0 = tid * 2, fl1 = fl0 + 1;
  const int kr0 = fl0 >> 5, mc0 = (fl0 & 31) * 4;
  const int kr1 = fl1 >> 5, mc1 = (fl1 & 31) * 4;

  float acc[8][8];
#pragma unroll
  for (int i = 0; i < 8; ++i)
#pragma unroll
    for (int j = 0; j < 8; ++j) acc[i][j] = 0.f;

  for (int k0 = 0; k0 < SEQ; k0 += 16) {
    float4 a0 = *(const float4*)&xb[(size_t)(k0 + kr0) * NF + m0 + mc0];
    float4 a1 = *(const float4*)&xb[(size_t)(k0 + kr1) * NF + m0 + mc1];
    float4 b0 = *(const float4*)&xb[(size_t)(k0 + kr0) * NF + n0 + mc0];
    float4 b1 = *(const float4*)&xb[(size_t)(k0 + kr1) * NF + n0 + mc1];
    __syncthreads();
    *(float4*)&As[kr0][mc0] = a0;
    *(float4*)&As[kr1][mc1] = a1;
    *(float4*)&Bs[kr0][mc0] = b0;
    *(float4*)&Bs[kr1][mc1] = b1;
    __syncthreads();
#pragma unroll
    for (int k = 0; k < 16; ++k) {
      float4 av0 = *(float4*)&As[k][ty * 4];
      float4 av1 = *(float4*)&As[k][64 + ty * 4];
      float4 bv0 = *(float4*)&Bs[k][tx * 4];
      float4 bv1 = *(float4*)&Bs[k][64 + tx * 4];
      float aa[8] = {av0.x, av0.y, av0.z, av0.w, av1.x, av1.y, av1.z, av1.w};
      float bb[8] = {bv0.x, bv0.y, bv0.z, bv0.w, bv1.x, bv1.y, bv1.z, bv1.w};
#pragma unroll
      for (int i = 0; i < 8; ++i)
#pragma unroll
        for (int j = 0; j < 8; ++j) acc[i][j] = fmaf(aa[i], bb[j], acc[i][j]);
    }
  }

  float* Gb = G + (size_t)b * NF * NF;
#pragma unroll
  for (int i = 0; i < 8; ++i) {
    const int row = m0 + ((i >> 2) << 6) + ty * 4 + (i & 3);
#pragma unroll
    for (int jg = 0; jg < 2; ++jg) {
      const int col = n0 + jg * 64 + tx * 4;
      float4 r = {acc[i][jg * 4 + 0], acc[i][jg * 4 + 1],
                  acc[i][jg * 4 + 2], acc[i][jg * 4 + 3]};
      *(float4*)&Gb[(size_t)row * NF + col] = r;
    }
  }
}

// ---------------------------------------------------------------------------
// Generic batched NN gemm: C[z] = A[z][M,K] @ B[z][K,N] (+ bias[z][N]).
// 128x128 tile, BK=16, 256 threads, split-4 microtile. Exact fit assumed.
// ---------------------------------------------------------------------------
__global__ __launch_bounds__(256) void gemm_nn_kernel(
    const float* __restrict__ A, int lda, long long sA,
    const float* __restrict__ B, int ldb, long long sB,
    const float* __restrict__ bias, long long sBias,
    float* __restrict__ C, int ldc, long long sC, int K) {
  const int z = blockIdx.z;
  const float* Az = A + (size_t)z * sA;
  const float* Bz = B + (size_t)z * sB;
  float* Cz = C + (size_t)z * sC;
  const int m0 = blockIdx.y * 128, n0 = blockIdx.x * 128;
  __shared__ float As[16][128];       // transposed A tile: As[k][m]
  __shared__ float Bs[16][132];
  const int tid = threadIdx.x, tx = tid & 15, ty = tid >> 4;
  const int fl0 = tid * 2, fl1 = fl0 + 1;
  const int ar0 = fl0 >> 2, ak0 = (fl0 & 3) * 4;
  const int ar1 = fl1 >> 2, ak1 = (fl1 & 3) * 4;
  const int bk0 = fl0 >> 5, bn0 = (fl0 & 31) * 4;
  const int bk1 = fl1 >> 5, bn1 = (fl1 & 31) * 4;

  float acc[8][8];
#pragma unroll
  for (int i = 0; i < 8; ++i)
#pragma unroll
    for (int j = 0; j < 8; ++j) acc[i][j] = 0.f;

  for (int k0 = 0; k0 < K; k0 += 16) {
    float4 a0 = *(const float4*)&Az[(size_t)(m0 + ar0) * lda + k0 + ak0];
    float4 a1 = *(const float4*)&Az[(size_t)(m0 + ar1) * lda + k0 + ak1];
    float4 b0 = *(const float4*)&Bz[(size_t)(k0 + bk0) * ldb + n0 + bn0];
    float4 b1 = *(const float4*)&Bz[(size_t)(k0 + bk1) * ldb + n0 + bn1];
    __syncthreads();
    As[ak0 + 0][ar0] = a0.x; As[ak0 + 1][ar0] = a0.y;
    As[ak0 + 2][ar0] = a0.z; As[ak0 + 3][ar0] = a0.w;
    As[ak1 + 0][ar1] = a1.x; As[ak1 + 1][ar1] = a1.y;
    As[ak1 + 2][ar1] = a1.z; As[ak1 + 3][ar1] = a1.w;
    *(float4*)&Bs[bk0][bn0] = b0;
    *(float4*)&Bs[bk1][bn1] = b1;
    __syncthreads();
#pragma unroll
    for (int k = 0; k < 16; ++k) {
      float4 av0 = *(float4*)&As[k][ty * 4];
      float4 av1 = *(float4*)&As[k][64 + ty * 4];
      float4 bv0 = *(float4*)&Bs[k][tx * 4];
      float4 bv1 = *(float4*)&Bs[k][64 + tx * 4];
      float aa[8] = {av0.x, av0.y, av0.z, av0.w, av1.x, av1.y, av1.z, av1.w};
      float bb[8] = {bv0.x, bv0.y, bv0.z, bv0.w, bv1.x, bv1.y, bv1.z, bv1.w};
#pragma unroll
      for (int i = 0; i < 8; ++i)
#pragma unroll
        for (int j = 0; j < 8; ++j) acc[i][j] = fmaf(aa[i], bb[j], acc[i][j]);
    }
  }

#pragma unroll
  for (int i = 0; i < 8; ++i) {
    const int row = m0 + ((i >> 2) << 6) + ty * 4 + (i & 3);
#pragma unroll
    for (int jg = 0; jg < 2; ++jg) {
      const int col = n0 + jg * 64 + tx * 4;
      float4 r = {acc[i][jg * 4 + 0], acc[i][jg * 4 + 1],
                  acc[i][jg * 4 + 2], acc[i][jg * 4 + 3]};
      if (bias) {
        const float* bz = bias + (size_t)z * sBias;
        r.x += bz[col + 0]; r.y += bz[col + 1];
        r.z += bz[col + 2]; r.w += bz[col + 3];
      }
      *(float4*)&Cz[(size_t)row * ldc + col] = r;
    }
  }
}

// ---------------------------------------------------------------------------
// Scores + softmax per (h,b): S = Wq_h^T U_h + bias corrections, scale 1/8,
// softmax over d (rows), emit A[hb][64][64] and bvA[hb][64] = bv_h @ A.
// grid 256 (hb = h*32+b), 256 threads.
// ---------------------------------------------------------------------------
__global__ __launch_bounds__(256) void score_softmax_kernel(
    const float* __restrict__ Wq_all, const float* __restrict__ U,
    const float* __restrict__ pq, const float* __restrict__ pk,
    const float* __restrict__ bq, const float* __restrict__ bk,
    const float* __restrict__ bv,
    float* __restrict__ Amat, float* __restrict__ bvA) {
  const int hb = blockIdx.x;
  const int h = hb >> 5, b = hb & 31;
  __shared__ float Qs[64][65];
  __shared__ float Us[64][65];
  __shared__ float Ss[64][65];
  const int tid = threadIdx.x, eg = tid & 15, dg = tid >> 4;
  const float* Ub = U + (size_t)b * NF * NF;

  float acc[4][4];
#pragma unroll
  for (int i = 0; i < 4; ++i)
#pragma unroll
    for (int j = 0; j < 4; ++j) acc[i][j] = 0.f;

  for (int f0 = 0; f0 < NF; f0 += 64) {
#pragma unroll
    for (int q = 0; q < 4; ++q) {
      const int idx = q * 256 + tid;
      const int fi = idx >> 4, dd = (idx & 15) * 4;
      *(float4*)&Qs[fi][dd] = *(const float4*)&Wq_all[(size_t)(f0 + fi) * NF + h * HD + dd];
      *(float4*)&Us[fi][dd] = *(const float4*)&Ub[(size_t)(f0 + fi) * NF + h * HD + dd];
    }
    __syncthreads();
#pragma unroll 16
    for (int fi = 0; fi < 64; ++fi) {
      float4 qa = *(float4*)&Qs[fi][dg * 4];
      float4 ub = *(float4*)&Us[fi][eg * 4];
      float qa_[4] = {qa.x, qa.y, qa.z, qa.w};
      float ub_[4] = {ub.x, ub.y, ub.z, ub.w};
#pragma unroll
      for (int i = 0; i < 4; ++i)
#pragma unroll
        for (int j = 0; j < 4; ++j) acc[i][j] = fmaf(qa_[i], ub_[j], acc[i][j]);
    }
    __syncthreads();
  }

  // bias corrections: S += bq[d]*pk[e] + bk[e]*pq[d] + L*bq[d]*bk[e]; scale 1/8
#pragma unroll
  for (int i = 0; i < 4; ++i) {
    const int d = dg * 4 + i;
    const float bqv = bq[h * HD + d];
    const float pqv = pq[(size_t)b * NF + h * HD + d];
#pragma unroll
    for (int j = 0; j < 4; ++j) {
      const int e = eg * 4 + j;
      const float bkv = bk[h * HD + e];
      const float pkv = pk[(size_t)b * NF + h * HD + e];
      float v = acc[i][j] + bqv * pkv + bkv * pqv + 4096.f * bqv * bkv;
      Ss[d][e] = v * 0.125f;
    }
  }
  __syncthreads();

  if (tid < 64) {
    const int e = tid;
    float m = -INFINITY;
    for (int d = 0; d < 64; ++d) m = fmaxf(m, Ss[d][e]);
    float sum = 0.f;
    for (int d = 0; d < 64; ++d) {
      float ex = __expf(Ss[d][e] - m);
      Ss[d][e] = ex;
      sum += ex;
    }
    const float inv = 1.f / sum;
    float bacc = 0.f;
    for (int d = 0; d < 64; ++d) {
      const float a = Ss[d][e] * inv;
      Amat[(size_t)hb * 4096 + d * 64 + e] = a;
      bacc = fmaf(bv[h * HD + d], a, bacc);
    }
    bvA[(size_t)hb * HD + e] = bacc;
  }
}

// ---------------------------------------------------------------------------
// WvA[hb][f][e] = sum_d Wv_all[f][h*64+d] * A[hb][d][e].  K=64.
// grid (4 f-chunks, 256 hb), 256 threads, [128 f][64 e] per block.
// ---------------------------------------------------------------------------
__global__ __launch_bounds__(256) void wva_kernel(
    const float* __restrict__ Wv_all, const float* __restrict__ Amat,
    float* __restrict__ WvA) {
  const int hb = blockIdx.y, h = hb >> 5;
  const int f0 = blockIdx.x * 128;
  __shared__ float Ws[128][65];
  __shared__ float As[64][65];
  const int tid = threadIdx.x;

  // load A tile [64][64]
#pragma unroll
  for (int q = 0; q < 4; ++q) {
    const int idx = q * 256 + tid;
    const int d = idx >> 4, ee = (idx & 15) * 4;
    *(float4*)&As[d][ee] = *(const float4*)&Amat[(size_t)hb * 4096 + d * 64 + ee];
  }
  // load Wv tile [128][64]
#pragma unroll
  for (int q = 0; q < 8; ++q) {
    const int idx = q * 256 + tid;
    const int fi = idx >> 4, dd = (idx & 15) * 4;
    *(float4*)&Ws[fi][dd] = *(const float4*)&Wv_all[(size_t)(f0 + fi) * NF + h * HD + dd];
  }
  __syncthreads();

  const int fg = tid >> 4, eg = tid & 15;   // 8 f-rows, 4 e-cols per thread
  float acc[8][4];
#pragma unroll
  for (int i = 0; i < 8; ++i)
#pragma unroll
    for (int j = 0; j < 4; ++j) acc[i][j] = 0.f;
#pragma unroll 8
  for (int d = 0; d < 64; ++d) {
    float4 av = *(float4*)&As[d][eg * 4];
    float a_[4] = {av.x, av.y, av.z, av.w};
#pragma unroll
    for (int i = 0; i < 8; ++i) {
      const float w = Ws[fg * 8 + i][d];
#pragma unroll
      for (int j = 0; j < 4; ++j) acc[i][j] = fmaf(w, a_[j], acc[i][j]);
    }
  }
  float* o = WvA + (size_t)hb * NF * HD + (size_t)(f0 + fg * 8) * HD + eg * 4;
#pragma unroll
  for (int i = 0; i < 8; ++i) {
    float4 r = {acc[i][0], acc[i][1], acc[i][2], acc[i][3]};
    *(float4*)&o[(size_t)i * HD] = r;
  }
}

// ---------------------------------------------------------------------------
// heads[hb][l][e] = x[b][l][:] @ WvA[hb][:,e] + bvA[hb][e].
// [4096 x 64] per hb, K=512. grid (32 l-blocks, 256 bh=b*8+h), 256 threads.
// heads flat layout [h][b][l][e] == the torch-faithful [131072][512] reshape.
// ---------------------------------------------------------------------------
__global__ __launch_bounds__(256) void heads_kernel(
    const float* __restrict__ x, const float* __restrict__ WvA,
    const float* __restrict__ bvA, float* __restrict__ heads) {
  const int bh = blockIdx.y;            // b-major for x L2 reuse across h
  const int b = bh >> 3, h = bh & 7;
  const int hb = h * 32 + b;            // storage order
  const int m0 = blockIdx.x * 128;
  __shared__ float As[16][128];
  __shared__ float Bs[16][64];
  const int tid = threadIdx.x, tx = tid & 15, ty = tid >> 4;
  const float* xb = x + ((size_t)b * SEQ + m0) * NF;
  const float* Wp = WvA + (size_t)hb * NF * HD;
  const int fl0 = tid * 2, fl1 = fl0 + 1;
  const int ar0 = fl0 >> 2, ak0 = (fl0 & 3) * 4;
  const int ar1 = fl1 >> 2, ak1 = (fl1 & 3) * 4;
  const int bk = tid >> 4, bn = (tid & 15) * 4;

  float acc[8][4];
#pragma unroll
  for (int i = 0; i < 8; ++i)
#pragma unroll
    for (int j = 0; j < 4; ++j) acc[i][j] = 0.f;

  for (int k0 = 0; k0 < NF; k0 += 16) {
    float4 a0 = *(const float4*)&xb[(size_t)ar0 * NF + k0 + ak0];
    float4 a1 = *(const float4*)&xb[(size_t)ar1 * NF + k0 + ak1];
    float4 b0 = *(const float4*)&Wp[(size_t)(k0 + bk) * HD + bn];
    __syncthreads();
    As[ak0 + 0][ar0] = a0.x; As[ak0 + 1][ar0] = a0.y;
    As[ak0 + 2][ar0] = a0.z; As[ak0 + 3][ar0] = a0.w;
    As[ak1 + 0][ar1] = a1.x; As[ak1 + 1][ar1] = a1.y;
    As[ak1 + 2][ar1] = a1.z; As[ak1 + 3][ar1] = a1.w;
    *(float4*)&Bs[bk][bn] = b0;
    __syncthreads();
#pragma unroll
    for (int k = 0; k < 16; ++k) {
      float4 av0 = *(float4*)&As[k][ty * 4];
      float4 av1 = *(float4*)&As[k][64 + ty * 4];
      float4 bv4 = *(float4*)&Bs[k][tx * 4];
      float aa[8] = {av0.x, av0.y, av0.z, av0.w, av1.x, av1.y, av1.z, av1.w};
      float bb[4] = {bv4.x, bv4.y, bv4.z, bv4.w};
#pragma unroll
      for (int i = 0; i < 8; ++i)
#pragma unroll
        for (int j = 0; j < 4; ++j) acc[i][j] = fmaf(aa[i], bb[j], acc[i][j]);
    }
  }

  const float4 bva = *(const float4*)&bvA[(size_t)hb * HD + tx * 4];
  float* hp = heads + ((size_t)hb * SEQ + m0) * HD;
#pragma unroll
  for (int i = 0; i < 8; ++i) {
    const int row = ((i >> 2) << 6) + ty * 4 + (i & 3);
    float4 r = {acc[i][0] + bva.x, acc[i][1] + bva.y,
                acc[i][2] + bva.z, acc[i][3] + bva.w};
    *(float4*)&hp[(size_t)row * HD + tx * 4] = r;
  }
}

// ---------------------------------------------------------------------------
// kernel_launch
// ---------------------------------------------------------------------------
extern "C" void kernel_launch(void* const* d_in, const int* in_sizes, int n_in,
                              void* d_out, int out_size, void* d_ws, size_t ws_size,
                              hipStream_t stream) {
  const float* x  = (const float*)d_in[0];
  const float* Wq = (const float*)d_in[1];
  const float* bq = (const float*)d_in[2];
  const float* Wk = (const float*)d_in[3];
  const float* bk = (const float*)d_in[4];
  const float* Wv = (const float*)d_in[5];
  const float* bv = (const float*)d_in[6];
  const float* Wo = (const float*)d_in[7];
  const float* bo = (const float*)d_in[8];
  float* out = (float*)d_out;
  (void)in_sizes; (void)n_in; (void)out_size; (void)ws_size;

  // workspace layout (floats), total ~360 MiB
  float* w = (float*)d_ws;
  size_t off = 0;
  float* Wq_all = w + off; off += (size_t)NF * NF;          // 1 MiB
  float* Wk_all = w + off; off += (size_t)NF * NF;
  float* Wv_all = w + off; off += (size_t)NF * NF;
  float* s_part = w + off; off += (size_t)BATCH * 16 * NF;  // 1 MiB
  float* pq     = w + off; off += (size_t)BATCH * NF;
  float* pk     = w + off; off += (size_t)BATCH * NF;
  float* G      = w + off; off += (size_t)BATCH * NF * NF;  // 32 MiB
  float* U      = w + off; off += (size_t)BATCH * NF * NF;  // 32 MiB
  float* Amat   = w + off; off += (size_t)256 * 64 * 64;    // 4 MiB
  float* bvA    = w + off; off += (size_t)256 * 64;
  float* WvA    = w + off; off += (size_t)256 * NF * HD;    // 32 MiB
  float* heads  = w + off; off += ((size_t)1 << 26);        // 256 MiB

  // 1. pack weights
  pack3_kernel<<<(NF * NF + 255) / 256, 256, 0, stream>>>(Wq, Wk, Wv,
                                                          Wq_all, Wk_all, Wv_all);
  // 2. column sums of x (two-stage)
  colsum_kernel<<<dim3(BATCH, 16), 256, 0, stream>>>(x, s_part);
  // 3. Gram matrices G[b] = x[b]^T x[b]
  gram_kernel<<<dim3(4, 4, BATCH), 256, 0, stream>>>(x, G);
  // 4. p_q/p_k row vectors
  pqk_kernel<<<BATCH, 256, 0, stream>>>(s_part, Wq_all, Wk_all, pq, pk);
  // 5. U[b] = G[b] @ Wk_all
  gemm_nn_kernel<<<dim3(4, 4, BATCH), 256, 0, stream>>>(
      G, NF, (long long)NF * NF, Wk_all, NF, 0, nullptr, 0,
      U, NF, (long long)NF * NF, NF);
  // 6. scores + softmax -> A, bvA
  score_softmax_kernel<<<256, 256, 0, stream>>>(Wq_all, U, pq, pk, bq, bk, bv,
                                                Amat, bvA);
  // 7. WvA[hb] = Wv_h @ A[hb]
  wva_kernel<<<dim3(4, 256), 256, 0, stream>>>(Wv_all, Amat, WvA);
  // 8. heads[hb] = x[b] @ WvA[hb] + bvA[hb]
  heads_kernel<<<dim3(32, 256), 256, 0, stream>>>(x, WvA, bvA, heads);
  // 9. out = Hview[131072x512] @ Wo + bo
  gemm_nn_kernel<<<dim3(4, 1024, 1), 256, 0, stream>>>(
      heads, NF, 0, Wo, NF, 0, bo, 0, out, NF, 0, NF);
}

// Round 5
// 1361.613 us; speedup vs baseline: 2.1306x; 2.1306x over previous
//
#include <hip/hip_runtime.h>
#include <hip/hip_bf16.h>
#include <cstdint>
#include <cstddef>

#define BATCH 32
#define SEQ   4096
#define NF    512
#define NH    8
#define HD    64

typedef __bf16 bf16x8 __attribute__((ext_vector_type(8)));
typedef float  f32x4  __attribute__((ext_vector_type(4)));

// Blocked LDS layout for MFMA fragments: chunk((mf,kg,r)) = ((mf*4+kg)*16+r),
// 16B per chunk. Consecutive-8-lane groups -> 8 distinct bank quads (conflict-free).
__device__ __forceinline__ int lds_off(int m, int kg) {
  return (((m >> 4) * 4 + kg) * 16 + (m & 15)) * 8;   // in bf16 units
}

// ---------------------------------------------------------------------------
// Staging: MODE 0 = BF16ROW (pre-split hi/lo, rows x k), MODE 1 = F32ROW
// (fp32 rows x k, convert on the fly), MODE 2 = F32COL (fp32 [k][m] source,
// per-lane column gather == coalesced across lanes; for gram's x^T panels).
// ---------------------------------------------------------------------------
template<int MODE>
__device__ __forceinline__ void stage_tile(
    const void* pa, const void* pb, long long zoff, int ld,
    long long row0, int k0, __bf16* sH, __bf16* sL, int tid)
{
  if constexpr (MODE == 0) {
    const __bf16* hi = (const __bf16*)pa + zoff;
    const __bf16* lo = (const __bf16*)pb + zoff;
    const int r = tid >> 1, half = tid & 1;
    const size_t base = (size_t)(row0 + r) * ld + k0 + half * 16;
    bf16x8 h0 = *(const bf16x8*)(hi + base);
    bf16x8 h1 = *(const bf16x8*)(hi + base + 8);
    bf16x8 l0 = *(const bf16x8*)(lo + base);
    bf16x8 l1 = *(const bf16x8*)(lo + base + 8);
    *(bf16x8*)&sH[lds_off(r, half * 2 + 0)] = h0;
    *(bf16x8*)&sH[lds_off(r, half * 2 + 1)] = h1;
    *(bf16x8*)&sL[lds_off(r, half * 2 + 0)] = l0;
    *(bf16x8*)&sL[lds_off(r, half * 2 + 1)] = l1;
  } else if constexpr (MODE == 1) {
    const float* A = (const float*)pa + zoff;
    const int r = tid >> 1, half = tid & 1;
    const float* src = A + (size_t)(row0 + r) * ld + k0 + half * 16;
    float f[16];
#pragma unroll
    for (int q = 0; q < 4; ++q) {
      float4 v = *(const float4*)&src[q * 4];
      f[q * 4 + 0] = v.x; f[q * 4 + 1] = v.y; f[q * 4 + 2] = v.z; f[q * 4 + 3] = v.w;
    }
#pragma unroll
    for (int q = 0; q < 2; ++q) {
      const int kg = half * 2 + q;
      bf16x8 vh, vl;
#pragma unroll
      for (int j = 0; j < 8; ++j) {
        float x = f[q * 8 + j];
        __bf16 h = (__bf16)x;
        vh[j] = h;
        vl[j] = (__bf16)(x - (float)h);
      }
      *(bf16x8*)&sH[lds_off(r, kg)] = vh;
      *(bf16x8*)&sL[lds_off(r, kg)] = vl;
    }
  } else {  // F32COL: src fp32 [k-rows][ld m-cols]; panel[m][k] = src[k][m]
    const float* A = (const float*)pa + zoff;
    const int m = tid & 127, lg = (tid >> 7) * 16;
    float f[16];
#pragma unroll
    for (int i = 0; i < 16; ++i)
      f[i] = A[(size_t)(k0 + lg + i) * ld + row0 + m];
#pragma unroll
    for (int q = 0; q < 2; ++q) {
      const int kg = (tid >> 7) * 2 + q;
      bf16x8 vh, vl;
#pragma unroll
      for (int j = 0; j < 8; ++j) {
        float x = f[q * 8 + j];
        __bf16 h = (__bf16)x;
        vh[j] = h;
        vl[j] = (__bf16)(x - (float)h);
      }
      *(bf16x8*)&sH[lds_off(m, kg)] = vh;
      *(bf16x8*)&sL[lds_off(m, kg)] = vl;
    }
  }
}

// ---------------------------------------------------------------------------
// Split-bf16 MFMA NT GEMM: C[z][m][n] = sum_k A[z][m][k] * B[z][n][k]
// (~fp32 accuracy: Ah*Bh + Al*Bh + Ah*Bl). 128x128 tile, BK=32, 4 waves 2x2,
// per-wave 64x64 via 4x4 frags of 16x16x32.
// EPI: 0 = f32 (U), 1 = f32 + bias[n] (out), 2 = bf16 hi/lo pair (G),
//      3 = heads (bf16 pair, bvA bias, [h][b][l][e] scatter)
// ---------------------------------------------------------------------------
template<int MA, int MB, int EPI>
__global__ __launch_bounds__(256) void mfma_nt(
    const void* Aa, const void* Ab, long long sA, int lda,
    const void* Ba, const void* Bb, long long sB, int ldb,
    const float* __restrict__ bias, void* C0, void* C1, long long sC, int K)
{
  __shared__ __bf16 sAh[4096], sAl[4096], sBh[4096], sBl[4096];
  const int tid = threadIdx.x;
  const int lane = tid & 63, wave = tid >> 6;
  const int wm = wave >> 1, wn = wave & 1;
  const int z = blockIdx.z;
  const long long m0 = (long long)blockIdx.y * 128;
  const int n0 = blockIdx.x * 128;

  f32x4 acc[4][4];
#pragma unroll
  for (int i = 0; i < 4; ++i)
#pragma unroll
    for (int j = 0; j < 4; ++j)
#pragma unroll
      for (int c = 0; c < 4; ++c) acc[i][j][c] = 0.f;

  const int kg = lane >> 4, r = lane & 15;

  for (int k0 = 0; k0 < K; k0 += 32) {
    __syncthreads();
    stage_tile<MA>(Aa, Ab, (long long)z * sA, lda, m0, k0, sAh, sAl, tid);
    stage_tile<MB>(Ba, Bb, (long long)z * sB, ldb, n0, k0, sBh, sBl, tid);
    __syncthreads();

    bf16x8 ah[4], al[4], bh[4], bl[4];
#pragma unroll
    for (int i = 0; i < 4; ++i) {
      ah[i] = *(const bf16x8*)&sAh[lds_off(wm * 64 + i * 16 + r, kg)];
      al[i] = *(const bf16x8*)&sAl[lds_off(wm * 64 + i * 16 + r, kg)];
      bh[i] = *(const bf16x8*)&sBh[lds_off(wn * 64 + i * 16 + r, kg)];
      bl[i] = *(const bf16x8*)&sBl[lds_off(wn * 64 + i * 16 + r, kg)];
    }
#pragma unroll
    for (int i = 0; i < 4; ++i)
#pragma unroll
      for (int j = 0; j < 4; ++j) {
        acc[i][j] = __builtin_amdgcn_mfma_f32_16x16x32_bf16(ah[i], bh[j], acc[i][j], 0, 0, 0);
        acc[i][j] = __builtin_amdgcn_mfma_f32_16x16x32_bf16(al[i], bh[j], acc[i][j], 0, 0, 0);
        acc[i][j] = __builtin_amdgcn_mfma_f32_16x16x32_bf16(ah[i], bl[j], acc[i][j], 0, 0, 0);
      }
  }

  // Epilogue. C/D layout: col = lane&15, row = (lane>>4)*4 + reg  [m89-verified]
  const int rbase = (lane >> 4) * 4;
  const int cn = lane & 15;
#pragma unroll
  for (int i = 0; i < 4; ++i) {
    const long long gm = m0 + wm * 64 + i * 16 + rbase;
#pragma unroll
    for (int j = 0; j < 4; ++j) {
      const int gn = n0 + wn * 64 + j * 16 + cn;
      if constexpr (EPI == 0) {
        float* C = (float*)C0 + (long long)z * sC;
#pragma unroll
        for (int rr = 0; rr < 4; ++rr)
          C[(size_t)(gm + rr) * 512 + gn] = acc[i][j][rr];
      } else if constexpr (EPI == 1) {
        float* C = (float*)C0;
        const float bv = bias[gn];
#pragma unroll
        for (int rr = 0; rr < 4; ++rr)
          C[(size_t)(gm + rr) * 512 + gn] = acc[i][j][rr] + bv;
      } else if constexpr (EPI == 2) {
        __bf16* Ch = (__bf16*)C0 + (long long)z * sC;
        __bf16* Cl = (__bf16*)C1 + (long long)z * sC;
#pragma unroll
        for (int rr = 0; rr < 4; ++rr) {
          float v = acc[i][j][rr];
          __bf16 h = (__bf16)v;
          Ch[(size_t)(gm + rr) * 512 + gn] = h;
          Cl[(size_t)(gm + rr) * 512 + gn] = (__bf16)(v - (float)h);
        }
      } else {  // heads: col n -> head h, e; row -> [h][b][l] flat
        const int h = gn >> 6, e = gn & 63;
        const float bv = bias[(h * 32 + z) * 64 + e];
        __bf16* Ch = (__bf16*)C0;
        __bf16* Cl = (__bf16*)C1;
        const size_t rowb = (size_t)(h * 32 + z) * 4096 + gm;
#pragma unroll
        for (int rr = 0; rr < 4; ++rr) {
          float v = acc[i][j][rr] + bv;
          __bf16 hh = (__bf16)v;
          Ch[(rowb + rr) * 64 + e] = hh;
          Cl[(rowb + rr) * 64 + e] = (__bf16)(v - (float)hh);
        }
      }
    }
  }
}

// ---------------------------------------------------------------------------
// Pack W{q,k,v} [H][F][D] -> [F][512] fp32; also Wk^T and Wo^T as bf16 hi/lo.
// ---------------------------------------------------------------------------
__global__ void pack3_kernel(const float* __restrict__ Wq, const float* __restrict__ Wk,
                             const float* __restrict__ Wv, const float* __restrict__ Wo,
                             float* __restrict__ Wq_all, float* __restrict__ Wk_all,
                             float* __restrict__ Wv_all,
                             __bf16* __restrict__ Wkt_h, __bf16* __restrict__ Wkt_l,
                             __bf16* __restrict__ Wot_h, __bf16* __restrict__ Wot_l) {
  int i = blockIdx.x * 256 + threadIdx.x;
  if (i >= NF * NF) return;
  int f = i >> 9, n = i & 511, h = n >> 6, d = n & 63;
  size_t src = ((size_t)h * NF + f) * HD + d;
  float wq = Wq[src], wk = Wk[src], wv = Wv[src];
  Wq_all[i] = wq;
  Wk_all[i] = wk;
  Wv_all[i] = wv;
  __bf16 kh = (__bf16)wk;
  Wkt_h[(size_t)n * 512 + f] = kh;
  Wkt_l[(size_t)n * 512 + f] = (__bf16)(wk - (float)kh);
  float wo = Wo[i];          // Wo[f][n], f = concat row, n = out col
  __bf16 oh = (__bf16)wo;
  Wot_h[(size_t)n * 512 + f] = oh;
  Wot_l[(size_t)n * 512 + f] = (__bf16)(wo - (float)oh);
}

// ---------------------------------------------------------------------------
// Column sums of x (two-stage) + p_q/p_k = s @ W (bias-correction vectors).
// ---------------------------------------------------------------------------
__global__ __launch_bounds__(256) void colsum_kernel(const float* __restrict__ x,
                                                     float* __restrict__ s_part) {
  const int b = blockIdx.x, c = blockIdx.y, t = threadIdx.x;
  const float* base = x + ((size_t)b * SEQ + c * 256) * NF;
  float a0 = 0.f, a1 = 0.f;
  for (int l = 0; l < 256; ++l) {
    a0 += base[(size_t)l * NF + t];
    a1 += base[(size_t)l * NF + t + 256];
  }
  float* o = s_part + ((size_t)b * 16 + c) * NF;
  o[t] = a0;
  o[t + 256] = a1;
}

__global__ __launch_bounds__(256) void pqk_kernel(
    const float* __restrict__ s_part, const float* __restrict__ Wq_all,
    const float* __restrict__ Wk_all, float* __restrict__ pq, float* __restrict__ pk) {
  const int b = blockIdx.x, t = threadIdx.x;
  __shared__ float s[512];
  float a0 = 0.f, a1 = 0.f;
  for (int c = 0; c < 16; ++c) {
    a0 += s_part[((size_t)b * 16 + c) * NF + t];
    a1 += s_part[((size_t)b * 16 + c) * NF + t + 256];
  }
  s[t] = a0;
  s[t + 256] = a1;
  __syncthreads();
  float q0 = 0.f, q1 = 0.f, k0 = 0.f, k1 = 0.f;
  for (int f = 0; f < NF; ++f) {
    const float sv = s[f];
    q0 += sv * Wq_all[(size_t)f * NF + t];
    q1 += sv * Wq_all[(size_t)f * NF + t + 256];
    k0 += sv * Wk_all[(size_t)f * NF + t];
    k1 += sv * Wk_all[(size_t)f * NF + t + 256];
  }
  pq[(size_t)b * NF + t] = q0;
  pq[(size_t)b * NF + t + 256] = q1;
  pk[(size_t)b * NF + t] = k0;
  pk[(size_t)b * NF + t + 256] = k1;
}

// ---------------------------------------------------------------------------
// Scores + softmax per (h,b) -> A[hb][64][64], bvA[hb][64]  (unchanged, fp32)
// ---------------------------------------------------------------------------
__global__ __launch_bounds__(256) void score_softmax_kernel(
    const float* __restrict__ Wq_all, const float* __restrict__ U,
    const float* __restrict__ pq, const float* __restrict__ pk,
    const float* __restrict__ bq, const float* __restrict__ bk,
    const float* __restrict__ bv,
    float* __restrict__ Amat, float* __restrict__ bvA) {
  const int hb = blockIdx.x;
  const int h = hb >> 5, b = hb & 31;
  __shared__ float Qs[64][65];
  __shared__ float Us[64][65];
  __shared__ float Ss[64][65];
  const int tid = threadIdx.x, eg = tid & 15, dg = tid >> 4;
  const float* Ub = U + (size_t)b * NF * NF;

  float acc[4][4];
#pragma unroll
  for (int i = 0; i < 4; ++i)
#pragma unroll
    for (int j = 0; j < 4; ++j) acc[i][j] = 0.f;

  for (int f0 = 0; f0 < NF; f0 += 64) {
#pragma unroll
    for (int q = 0; q < 4; ++q) {
      const int idx = q * 256 + tid;
      const int fi = idx >> 4, dd = (idx & 15) * 4;
      *(float4*)&Qs[fi][dd] = *(const float4*)&Wq_all[(size_t)(f0 + fi) * NF + h * HD + dd];
      *(float4*)&Us[fi][dd] = *(const float4*)&Ub[(size_t)(f0 + fi) * NF + h * HD + dd];
    }
    __syncthreads();
#pragma unroll 16
    for (int fi = 0; fi < 64; ++fi) {
      float4 qa = *(float4*)&Qs[fi][dg * 4];
      float4 ub = *(float4*)&Us[fi][eg * 4];
      float qa_[4] = {qa.x, qa.y, qa.z, qa.w};
      float ub_[4] = {ub.x, ub.y, ub.z, ub.w};
#pragma unroll
      for (int i = 0; i < 4; ++i)
#pragma unroll
        for (int j = 0; j < 4; ++j) acc[i][j] = fmaf(qa_[i], ub_[j], acc[i][j]);
    }
    __syncthreads();
  }

#pragma unroll
  for (int i = 0; i < 4; ++i) {
    const int d = dg * 4 + i;
    const float bqv = bq[h * HD + d];
    const float pqv = pq[(size_t)b * NF + h * HD + d];
#pragma unroll
    for (int j = 0; j < 4; ++j) {
      const int e = eg * 4 + j;
      const float bkv = bk[h * HD + e];
      const float pkv = pk[(size_t)b * NF + h * HD + e];
      float v = acc[i][j] + bqv * pkv + bkv * pqv + 4096.f * bqv * bkv;
      Ss[d][e] = v * 0.125f;
    }
  }
  __syncthreads();

  if (tid < 64) {
    const int e = tid;
    float m = -INFINITY;
    for (int d = 0; d < 64; ++d) m = fmaxf(m, Ss[d][e]);
    float sum = 0.f;
    for (int d = 0; d < 64; ++d) {
      float ex = __expf(Ss[d][e] - m);
      Ss[d][e] = ex;
      sum += ex;
    }
    const float inv = 1.f / sum;
    float bacc = 0.f;
    for (int d = 0; d < 64; ++d) {
      const float a = Ss[d][e] * inv;
      Amat[(size_t)hb * 4096 + d * 64 + e] = a;
      bacc = fmaf(bv[h * HD + d], a, bacc);
    }
    bvA[(size_t)hb * HD + e] = bacc;
  }
}

// ---------------------------------------------------------------------------
// WvA^T[b][n=h*64+e][f] (bf16 hi/lo) = sum_d Wv_all[f][h*64+d] * A[hb][d][e]
// ---------------------------------------------------------------------------
__global__ __launch_bounds__(256) void wva_kernel(
    const float* __restrict__ Wv_all, const float* __restrict__ Amat,
    __bf16* __restrict__ WvAt_h, __bf16* __restrict__ WvAt_l) {
  const int hb = blockIdx.y, h = hb >> 5, b = hb & 31;
  const int f0 = blockIdx.x * 128;
  __shared__ float Ws[128][65];
  __shared__ float As[64][65];
  const int tid = threadIdx.x;

#pragma unroll
  for (int q = 0; q < 4; ++q) {
    const int idx = q * 256 + tid;
    const int d = idx >> 4, ee = (idx & 15) * 4;
    *(float4*)&As[d][ee] = *(const float4*)&Amat[(size_t)hb * 4096 + d * 64 + ee];
  }
#pragma unroll
  for (int q = 0; q < 8; ++q) {
    const int idx = q * 256 + tid;
    const int fi = idx >> 4, dd = (idx & 15) * 4;
    *(float4*)&Ws[fi][dd] = *(const float4*)&Wv_all[(size_t)(f0 + fi) * NF + h * HD + dd];
  }
  __syncthreads();

  const int fg = tid >> 4, eg = tid & 15;
  float acc[8][4];
#pragma unroll
  for (int i = 0; i < 8; ++i)
#pragma unroll
    for (int j = 0; j < 4; ++j) acc[i][j] = 0.f;
#pragma unroll 8
  for (int d = 0; d < 64; ++d) {
    float4 av = *(float4*)&As[d][eg * 4];
    float a_[4] = {av.x, av.y, av.z, av.w};
#pragma unroll
    for (int i = 0; i < 8; ++i) {
      const float w = Ws[fg * 8 + i][d];
#pragma unroll
      for (int j = 0; j < 4; ++j) acc[i][j] = fmaf(w, a_[j], acc[i][j]);
    }
  }

  // transpose via LDS (reuse Ws as [64][130]) then coalesced bf16-pair store
  __syncthreads();
  float* Ts = &Ws[0][0];
#pragma unroll
  for (int i = 0; i < 8; ++i)
#pragma unroll
    for (int j = 0; j < 4; ++j)
      Ts[(eg * 4 + j) * 130 + fg * 8 + i] = acc[i][j];
  __syncthreads();

  const int e = tid >> 2, fs = (tid & 3) * 32;
  size_t orow = ((size_t)b * 512 + h * 64 + e) * 512 + f0 + fs;
#pragma unroll
  for (int c = 0; c < 4; ++c) {
    bf16x8 vh, vl;
#pragma unroll
    for (int j = 0; j < 8; ++j) {
      float v = Ts[e * 130 + fs + c * 8 + j];
      __bf16 hh = (__bf16)v;
      vh[j] = hh;
      vl[j] = (__bf16)(v - (float)hh);
    }
    *(bf16x8*)&WvAt_h[orow + c * 8] = vh;
    *(bf16x8*)&WvAt_l[orow + c * 8] = vl;
  }
}

// ---------------------------------------------------------------------------
// kernel_launch
// ---------------------------------------------------------------------------
extern "C" void kernel_launch(void* const* d_in, const int* in_sizes, int n_in,
                              void* d_out, int out_size, void* d_ws, size_t ws_size,
                              hipStream_t stream) {
  const float* x  = (const float*)d_in[0];
  const float* Wq = (const float*)d_in[1];
  const float* bq = (const float*)d_in[2];
  const float* Wk = (const float*)d_in[3];
  const float* bk = (const float*)d_in[4];
  const float* Wv = (const float*)d_in[5];
  const float* bv = (const float*)d_in[6];
  const float* Wo = (const float*)d_in[7];
  const float* bo = (const float*)d_in[8];
  float* out = (float*)d_out;
  (void)in_sizes; (void)n_in; (void)out_size; (void)ws_size;

  // workspace layout (float units), total ~362 MiB
  float* w = (float*)d_ws;
  size_t off = 0;
  float* Wq_all = w + off; off += 262144;
  float* Wk_all = w + off; off += 262144;
  float* Wv_all = w + off; off += 262144;
  float* s_part = w + off; off += 262144;
  float* pq     = w + off; off += 16384;
  float* pk     = w + off; off += 16384;
  float* U      = w + off; off += (size_t)32 * 262144;      // 32 MiB
  float* Amat   = w + off; off += 1048576;                  // 4 MiB
  float* bvA    = w + off; off += 16384;
  __bf16* Wkt_h = (__bf16*)(w + off); off += 131072;        // 512x512 bf16
  __bf16* Wkt_l = (__bf16*)(w + off); off += 131072;
  __bf16* Wot_h = (__bf16*)(w + off); off += 131072;
  __bf16* Wot_l = (__bf16*)(w + off); off += 131072;
  __bf16* Gh    = (__bf16*)(w + off); off += (size_t)32 * 131072;   // 16 MiB
  __bf16* Gl    = (__bf16*)(w + off); off += (size_t)32 * 131072;
  __bf16* WvAt_h= (__bf16*)(w + off); off += (size_t)32 * 131072;
  __bf16* WvAt_l= (__bf16*)(w + off); off += (size_t)32 * 131072;
  __bf16* Hh    = (__bf16*)(w + off); off += (size_t)131072 * 256;  // 128 MiB
  __bf16* Hl    = (__bf16*)(w + off); off += (size_t)131072 * 256;

  // 1. pack weights (+ transposed bf16 pairs)
  pack3_kernel<<<1024, 256, 0, stream>>>(Wq, Wk, Wv, Wo, Wq_all, Wk_all, Wv_all,
                                         Wkt_h, Wkt_l, Wot_h, Wot_l);
  // 2. column sums + bias-correction vectors
  colsum_kernel<<<dim3(BATCH, 16), 256, 0, stream>>>(x, s_part);
  pqk_kernel<<<BATCH, 256, 0, stream>>>(s_part, Wq_all, Wk_all, pq, pk);
  // 3. Gram pair: G[b] = x[b]^T x[b]  (both panels F32COL from x)
  mfma_nt<2, 2, 2><<<dim3(4, 4, BATCH), 256, 0, stream>>>(
      x, nullptr, (long long)SEQ * NF, NF,
      x, nullptr, (long long)SEQ * NF, NF,
      nullptr, Gh, Gl, 262144, SEQ);
  // 4. U[b] = G[b] @ Wk_all  (bf16 pairs)
  mfma_nt<0, 0, 0><<<dim3(4, 4, BATCH), 256, 0, stream>>>(
      Gh, Gl, 262144, NF,
      Wkt_h, Wkt_l, 0, NF,
      nullptr, U, nullptr, 262144, NF);
  // 5. scores + softmax -> A, bvA
  score_softmax_kernel<<<256, 256, 0, stream>>>(Wq_all, U, pq, pk, bq, bk, bv,
                                                Amat, bvA);
  // 6. WvA^T pair
  wva_kernel<<<dim3(4, 256), 256, 0, stream>>>(Wv_all, Amat, WvAt_h, WvAt_l);
  // 7. heads pair: x[b] @ WvAt[b]^T + bvA  -> [h][b][l][e] bf16 hi/lo
  mfma_nt<1, 0, 3><<<dim3(4, 32, BATCH), 256, 0, stream>>>(
      x, nullptr, (long long)SEQ * NF, NF,
      WvAt_h, WvAt_l, 262144, NF,
      bvA, Hh, Hl, 0, NF);
  // 8. out = Hview @ Wo + bo
  mfma_nt<0, 0, 1><<<dim3(4, 1024, 1), 256, 0, stream>>>(
      Hh, Hl, 0, NF,
      Wot_h, Wot_l, 0, NF,
      bo, out, nullptr, 0, NF);
}

// Round 9
// 1182.839 us; speedup vs baseline: 2.4526x; 1.1511x over previous
//
#include <hip/hip_runtime.h>
#include <hip/hip_bf16.h>
#include <cstdint>
#include <cstddef>

#define BATCH 32
#define SEQ   4096
#define NF    512
#define NH    8
#define HD    64

typedef __bf16 bf16x8 __attribute__((ext_vector_type(8)));
typedef float  f32x4  __attribute__((ext_vector_type(4)));

// Blocked LDS layout for MFMA fragments: chunk((mf,kg,r)) = ((mf*4+kg)*16+r),
// 16B per chunk. Frag reads are lane-contiguous 1024B per wave (conflict-free).
__device__ __forceinline__ int lds_off(int m, int kg) {
  return (((m >> 4) * 4 + kg) * 16 + (m & 15)) * 8;   // in bf16 units
}

// ---------------------------------------------------------------------------
// Staging modes: 0 = BF16ROW pair (hi/lo), 1 = F32ROW (convert in load phase),
// 2 = F32COL (column gather, for gram's x^T panels), 3 = BF16ROW hi-only.
// Split into load (global->reg, + cvt) and store (reg->LDS) so the next tile's
// loads overlap the current tile's ds_read+MFMA.
// ---------------------------------------------------------------------------
template<int MODE>
struct SRegs { bf16x8 h0, h1, l0, l1; };

__device__ __forceinline__ void cvt8(const float* f, bf16x8& vh, bf16x8& vl) {
#pragma unroll
  for (int j = 0; j < 8; ++j) {
    float x = f[j];
    __bf16 h = (__bf16)x;
    vh[j] = h;
    vl[j] = (__bf16)(x - (float)h);
  }
}

template<int MODE>
__device__ __forceinline__ SRegs<MODE> stage_load(
    const void* pa, const void* pb, long long zoff, int ld,
    long long row0, int k0, int tid)
{
  SRegs<MODE> R;
  if constexpr (MODE == 0 || MODE == 3) {
    const __bf16* hi = (const __bf16*)pa + zoff;
    const int r = tid >> 1, half = tid & 1;
    const size_t base = (size_t)(row0 + r) * ld + k0 + half * 16;
    R.h0 = *(const bf16x8*)(hi + base);
    R.h1 = *(const bf16x8*)(hi + base + 8);
    if constexpr (MODE == 0) {
      const __bf16* lo = (const __bf16*)pb + zoff;
      R.l0 = *(const bf16x8*)(lo + base);
      R.l1 = *(const bf16x8*)(lo + base + 8);
    }
  } else if constexpr (MODE == 1) {
    const float* A = (const float*)pa + zoff;
    const int r = tid >> 1, half = tid & 1;
    const float* src = A + (size_t)(row0 + r) * ld + k0 + half * 16;
    float f[16];
#pragma unroll
    for (int q = 0; q < 4; ++q) {
      float4 v = *(const float4*)&src[q * 4];
      f[q * 4 + 0] = v.x; f[q * 4 + 1] = v.y; f[q * 4 + 2] = v.z; f[q * 4 + 3] = v.w;
    }
    cvt8(f, R.h0, R.l0);
    cvt8(f + 8, R.h1, R.l1);
  } else {  // MODE 2: F32COL, panel[m][k] = src[k][m]
    const float* A = (const float*)pa + zoff;
    const int m = tid & 127, lg = (tid >> 7) * 16;
    float f[16];
#pragma unroll
    for (int i = 0; i < 16; ++i)
      f[i] = A[(size_t)(k0 + lg + i) * ld + row0 + m];
    cvt8(f, R.h0, R.l0);
    cvt8(f + 8, R.h1, R.l1);
  }
  return R;
}

template<int MODE>
__device__ __forceinline__ void stage_store(
    const SRegs<MODE>& R, __bf16* sH, __bf16* sL, int tid)
{
  if constexpr (MODE == 2) {
    const int m = tid & 127, kq = (tid >> 7) * 2;
    *(bf16x8*)&sH[lds_off(m, kq + 0)] = R.h0;
    *(bf16x8*)&sH[lds_off(m, kq + 1)] = R.h1;
    *(bf16x8*)&sL[lds_off(m, kq + 0)] = R.l0;
    *(bf16x8*)&sL[lds_off(m, kq + 1)] = R.l1;
  } else {
    const int r = tid >> 1, kq = (tid & 1) * 2;
    *(bf16x8*)&sH[lds_off(r, kq + 0)] = R.h0;
    *(bf16x8*)&sH[lds_off(r, kq + 1)] = R.h1;
    if constexpr (MODE != 3) {
      *(bf16x8*)&sL[lds_off(r, kq + 0)] = R.l0;
      *(bf16x8*)&sL[lds_off(r, kq + 1)] = R.l1;
    }
  }
}

// ---------------------------------------------------------------------------
// Split-bf16 MFMA NT GEMM: C[z][m][n] = sum_k A[z][m][k] * B[z][n][k]
// 128x128 tile, BK=32, 4 waves 2x2, 4x4 frags of 16x16x32 per wave.
// A-lo term skipped when MA==3 (2-term: Ah*Bh + Ah*Bl).
// EPI: 0 = f32 (U), 1 = f32 + bias[n] (out), 2 = bf16 hi/lo pair (G),
//      3 = heads (bf16 hi only, bvA bias, [h][b][l][e] scatter)
// XCD-chunked block swizzle: consecutive same-XCD blocks share the A panel.
// ---------------------------------------------------------------------------
template<int MA, int MB, int EPI>
__global__ __launch_bounds__(256) void mfma_nt(
    const void* Aa, const void* Ab, long long sA, int lda,
    const void* Ba, const void* Bb, long long sB, int ldb,
    const float* __restrict__ bias, void* C0, void* C1, long long sC, int K)
{
  constexpr bool AL = (MA != 3);
  __shared__ __bf16 smem[(AL ? 4 : 3) * 4096];
  __bf16* sAh = smem;
  __bf16* sBh = smem + 4096;
  __bf16* sBl = smem + 8192;
  __bf16* sAl = AL ? (smem + 12288) : smem;   // unused alias when !AL

  const int tid = threadIdx.x;
  const int lane = tid & 63, wave = tid >> 6;
  const int wm = wave >> 1, wn = wave & 1;

  // XCD-chunked swizzle (all grids are multiples of 8)
  const unsigned nx = gridDim.x, ny = gridDim.y;
  const unsigned nwg = nx * ny * gridDim.z;
  unsigned bid = blockIdx.x + nx * (blockIdx.y + ny * blockIdx.z);
  unsigned nid = (bid & 7) * (nwg >> 3) + (bid >> 3);
  const unsigned bx = nid % nx;
  unsigned t = nid / nx;
  const unsigned by = t % ny;
  const unsigned z = t / ny;

  const long long m0 = (long long)by * 128;
  const int n0 = bx * 128;
  const long long zA = (long long)z * sA, zB = (long long)z * sB;

  f32x4 acc[4][4];
#pragma unroll
  for (int i = 0; i < 4; ++i)
#pragma unroll
    for (int j = 0; j < 4; ++j)
#pragma unroll
      for (int c = 0; c < 4; ++c) acc[i][j][c] = 0.f;

  const int kg = lane >> 4, r = lane & 15;

  SRegs<MA> ra = stage_load<MA>(Aa, Ab, zA, lda, m0, 0, tid);
  SRegs<MB> rb = stage_load<MB>(Ba, Bb, zB, ldb, n0, 0, tid);

  for (int k0 = 0; k0 < K; k0 += 32) {
    __syncthreads();   // previous iteration's LDS reads complete
    stage_store<MA>(ra, sAh, sAl, tid);
    stage_store<MB>(rb, sBh, sBl, tid);
    __syncthreads();
    if (k0 + 32 < K) {   // prefetch next tile (overlaps ds_read + MFMA below)
      ra = stage_load<MA>(Aa, Ab, zA, lda, m0, k0 + 32, tid);
      rb = stage_load<MB>(Ba, Bb, zB, ldb, n0, k0 + 32, tid);
    }

    bf16x8 ah[4], al[4], bh[4], bl[4];
#pragma unroll
    for (int i = 0; i < 4; ++i) {
      ah[i] = *(const bf16x8*)&sAh[lds_off(wm * 64 + i * 16 + r, kg)];
      if constexpr (AL)
        al[i] = *(const bf16x8*)&sAl[lds_off(wm * 64 + i * 16 + r, kg)];
      bh[i] = *(const bf16x8*)&sBh[lds_off(wn * 64 + i * 16 + r, kg)];
      bl[i] = *(const bf16x8*)&sBl[lds_off(wn * 64 + i * 16 + r, kg)];
    }
#pragma unroll
    for (int i = 0; i < 4; ++i)
#pragma unroll
      for (int j = 0; j < 4; ++j) {
        acc[i][j] = __builtin_amdgcn_mfma_f32_16x16x32_bf16(ah[i], bh[j], acc[i][j], 0, 0, 0);
        if constexpr (AL)
          acc[i][j] = __builtin_amdgcn_mfma_f32_16x16x32_bf16(al[i], bh[j], acc[i][j], 0, 0, 0);
        acc[i][j] = __builtin_amdgcn_mfma_f32_16x16x32_bf16(ah[i], bl[j], acc[i][j], 0, 0, 0);
      }
  }

  // Epilogue. C/D layout: col = lane&15, row = (lane>>4)*4 + reg  [m89-verified]
  const int rbase = (lane >> 4) * 4;
  const int cn = lane & 15;
#pragma unroll
  for (int i = 0; i < 4; ++i) {
    const long long gm = m0 + wm * 64 + i * 16 + rbase;
#pragma unroll
    for (int j = 0; j < 4; ++j) {
      const int gn = n0 + wn * 64 + j * 16 + cn;
      if constexpr (EPI == 0) {
        float* C = (float*)C0 + (long long)z * sC;
#pragma unroll
        for (int rr = 0; rr < 4; ++rr)
          C[(size_t)(gm + rr) * 512 + gn] = acc[i][j][rr];
      } else if constexpr (EPI == 1) {
        float* C = (float*)C0;
        const float bv = bias[gn];
#pragma unroll
        for (int rr = 0; rr < 4; ++rr)
          C[(size_t)(gm + rr) * 512 + gn] = acc[i][j][rr] + bv;
      } else if constexpr (EPI == 2) {
        __bf16* Ch = (__bf16*)C0 + (long long)z * sC;
        __bf16* Cl = (__bf16*)C1 + (long long)z * sC;
#pragma unroll
        for (int rr = 0; rr < 4; ++rr) {
          float v = acc[i][j][rr];
          __bf16 h = (__bf16)v;
          Ch[(size_t)(gm + rr) * 512 + gn] = h;
          Cl[(size_t)(gm + rr) * 512 + gn] = (__bf16)(v - (float)h);
        }
      } else {  // heads: col n -> head h, e; row -> [h][b][l] flat; hi only
        const int h = gn >> 6, e = gn & 63;
        const float bv = bias[(h * 32 + (int)z) * 64 + e];
        __bf16* Ch = (__bf16*)C0;
        const size_t rowb = (size_t)(h * 32 + (int)z) * 4096 + gm;
#pragma unroll
        for (int rr = 0; rr < 4; ++rr)
          Ch[(rowb + rr) * 64 + e] = (__bf16)(acc[i][j][rr] + bv);
      }
    }
  }
}

// ---------------------------------------------------------------------------
// Pack W{q,k,v} [H][F][D] -> [F][512] fp32; also Wk^T and Wo^T as bf16 hi/lo.
// ---------------------------------------------------------------------------
__global__ void pack3_kernel(const float* __restrict__ Wq, const float* __restrict__ Wk,
                             const float* __restrict__ Wv, const float* __restrict__ Wo,
                             float* __restrict__ Wq_all, float* __restrict__ Wk_all,
                             float* __restrict__ Wv_all,
                             __bf16* __restrict__ Wkt_h, __bf16* __restrict__ Wkt_l,
                             __bf16* __restrict__ Wot_h, __bf16* __restrict__ Wot_l) {
  int i = blockIdx.x * 256 + threadIdx.x;
  if (i >= NF * NF) return;
  int f = i >> 9, n = i & 511, h = n >> 6, d = n & 63;
  size_t src = ((size_t)h * NF + f) * HD + d;
  float wq = Wq[src], wk = Wk[src], wv = Wv[src];
  Wq_all[i] = wq;
  Wk_all[i] = wk;
  Wv_all[i] = wv;
  __bf16 kh = (__bf16)wk;
  Wkt_h[(size_t)n * 512 + f] = kh;
  Wkt_l[(size_t)n * 512 + f] = (__bf16)(wk - (float)kh);
  float wo = Wo[i];          // Wo[f][n], f = concat row, n = out col
  __bf16 oh = (__bf16)wo;
  Wot_h[(size_t)n * 512 + f] = oh;
  Wot_l[(size_t)n * 512 + f] = (__bf16)(wo - (float)oh);
}

// ---------------------------------------------------------------------------
// Column sums of x (two-stage) + p_q/p_k = s @ W (bias-correction vectors).
// ---------------------------------------------------------------------------
__global__ __launch_bounds__(256) void colsum_kernel(const float* __restrict__ x,
                                                     float* __restrict__ s_part) {
  const int b = blockIdx.x, c = blockIdx.y, t = threadIdx.x;
  const float* base = x + ((size_t)b * SEQ + c * 256) * NF;
  float a0 = 0.f, a1 = 0.f;
  for (int l = 0; l < 256; ++l) {
    a0 += base[(size_t)l * NF + t];
    a1 += base[(size_t)l * NF + t + 256];
  }
  float* o = s_part + ((size_t)b * 16 + c) * NF;
  o[t] = a0;
  o[t + 256] = a1;
}

__global__ __launch_bounds__(256) void pqk_kernel(
    const float* __restrict__ s_part, const float* __restrict__ Wq_all,
    const float* __restrict__ Wk_all, float* __restrict__ pq, float* __restrict__ pk) {
  const int b = blockIdx.x, t = threadIdx.x;
  __shared__ float s[512];
  float a0 = 0.f, a1 = 0.f;
  for (int c = 0; c < 16; ++c) {
    a0 += s_part[((size_t)b * 16 + c) * NF + t];
    a1 += s_part[((size_t)b * 16 + c) * NF + t + 256];
  }
  s[t] = a0;
  s[t + 256] = a1;
  __syncthreads();
  float q0 = 0.f, q1 = 0.f, k0 = 0.f, k1 = 0.f;
  for (int f = 0; f < NF; ++f) {
    const float sv = s[f];
    q0 += sv * Wq_all[(size_t)f * NF + t];
    q1 += sv * Wq_all[(size_t)f * NF + t + 256];
    k0 += sv * Wk_all[(size_t)f * NF + t];
    k1 += sv * Wk_all[(size_t)f * NF + t + 256];
  }
  pq[(size_t)b * NF + t] = q0;
  pq[(size_t)b * NF + t + 256] = q1;
  pk[(size_t)b * NF + t] = k0;
  pk[(size_t)b * NF + t + 256] = k1;
}

// ---------------------------------------------------------------------------
// Scores + softmax per (h,b) -> A[hb][64][64], bvA[hb][64]  (fp32)
// ---------------------------------------------------------------------------
__global__ __launch_bounds__(256) void score_softmax_kernel(
    const float* __restrict__ Wq_all, const float* __restrict__ U,
    const float* __restrict__ pq, const float* __restrict__ pk,
    const float* __restrict__ bq, const float* __restrict__ bk,
    const float* __restrict__ bv,
    float* __restrict__ Amat, float* __restrict__ bvA) {
  const int hb = blockIdx.x;
  const int h = hb >> 5, b = hb & 31;
  __shared__ float Qs[64][65];
  __shared__ float Us[64][65];
  __shared__ float Ss[64][65];
  const int tid = threadIdx.x, eg = tid & 15, dg = tid >> 4;
  const float* Ub = U + (size_t)b * NF * NF;

  float acc[4][4];
#pragma unroll
  for (int i = 0; i < 4; ++i)
#pragma unroll
    for (int j = 0; j < 4; ++j) acc[i][j] = 0.f;

  for (int f0 = 0; f0 < NF; f0 += 64) {
#pragma unroll
    for (int q = 0; q < 4; ++q) {
      const int idx = q * 256 + tid;
      const int fi = idx >> 4, dd = (idx & 15) * 4;
      *(float4*)&Qs[fi][dd] = *(const float4*)&Wq_all[(size_t)(f0 + fi) * NF + h * HD + dd];
      *(float4*)&Us[fi][dd] = *(const float4*)&Ub[(size_t)(f0 + fi) * NF + h * HD + dd];
    }
    __syncthreads();
#pragma unroll 16
    for (int fi = 0; fi < 64; ++fi) {
      float4 qa = *(float4*)&Qs[fi][dg * 4];
      float4 ub = *(float4*)&Us[fi][eg * 4];
      float qa_[4] = {qa.x, qa.y, qa.z, qa.w};
      float ub_[4] = {ub.x, ub.y, ub.z, ub.w};
#pragma unroll
      for (int i = 0; i < 4; ++i)
#pragma unroll
        for (int j = 0; j < 4; ++j) acc[i][j] = fmaf(qa_[i], ub_[j], acc[i][j]);
    }
    __syncthreads();
  }

#pragma unroll
  for (int i = 0; i < 4; ++i) {
    const int d = dg * 4 + i;
    const float bqv = bq[h * HD + d];
    const float pqv = pq[(size_t)b * NF + h * HD + d];
#pragma unroll
    for (int j = 0; j < 4; ++j) {
      const int e = eg * 4 + j;
      const float bkv = bk[h * HD + e];
      const float pkv = pk[(size_t)b * NF + h * HD + e];
      float v = acc[i][j] + bqv * pkv + bkv * pqv + 4096.f * bqv * bkv;
      Ss[d][e] = v * 0.125f;
    }
  }
  __syncthreads();

  if (tid < 64) {
    const int e = tid;
    float m = -INFINITY;
    for (int d = 0; d < 64; ++d) m = fmaxf(m, Ss[d][e]);
    float sum = 0.f;
    for (int d = 0; d < 64; ++d) {
      float ex = __expf(Ss[d][e] - m);
      Ss[d][e] = ex;
      sum += ex;
    }
    const float inv = 1.f / sum;
    float bacc = 0.f;
    for (int d = 0; d < 64; ++d) {
      const float a = Ss[d][e] * inv;
      Amat[(size_t)hb * 4096 + d * 64 + e] = a;
      bacc = fmaf(bv[h * HD + d], a, bacc);
    }
    bvA[(size_t)hb * HD + e] = bacc;
  }
}

// ---------------------------------------------------------------------------
// WvA^T[b][n=h*64+e][f] (bf16 hi/lo) = sum_d Wv_all[f][h*64+d] * A[hb][d][e]
// ---------------------------------------------------------------------------
__global__ __launch_bounds__(256) void wva_kernel(
    const float* __restrict__ Wv_all, const float* __restrict__ Amat,
    __bf16* __restrict__ WvAt_h, __bf16* __restrict__ WvAt_l) {
  const int hb = blockIdx.y, h = hb >> 5, b = hb & 31;
  const int f0 = blockIdx.x * 128;
  __shared__ float Ws[128][65];
  __shared__ float As[64][65];
  const int tid = threadIdx.x;

#pragma unroll
  for (int q = 0; q < 4; ++q) {
    const int idx = q * 256 + tid;
    const int d = idx >> 4, ee = (idx & 15) * 4;
    *(float4*)&As[d][ee] = *(const float4*)&Amat[(size_t)hb * 4096 + d * 64 + ee];
  }
#pragma unroll
  for (int q = 0; q < 8; ++q) {
    const int idx = q * 256 + tid;
    const int fi = idx >> 4, dd = (idx & 15) * 4;
    *(float4*)&Ws[fi][dd] = *(const float4*)&Wv_all[(size_t)(f0 + fi) * NF + h * HD + dd];
  }
  __syncthreads();

  const int fg = tid >> 4, eg = tid & 15;
  float acc[8][4];
#pragma unroll
  for (int i = 0; i < 8; ++i)
#pragma unroll
    for (int j = 0; j < 4; ++j) acc[i][j] = 0.f;
#pragma unroll 8
  for (int d = 0; d < 64; ++d) {
    float4 av = *(float4*)&As[d][eg * 4];
    float a_[4] = {av.x, av.y, av.z, av.w};
#pragma unroll
    for (int i = 0; i < 8; ++i) {
      const float w = Ws[fg * 8 + i][d];
#pragma unroll
      for (int j = 0; j < 4; ++j) acc[i][j] = fmaf(w, a_[j], acc[i][j]);
    }
  }

  // transpose via LDS (reuse Ws as [64][130]) then coalesced bf16-pair store
  __syncthreads();
  float* Ts = &Ws[0][0];
#pragma unroll
  for (int i = 0; i < 8; ++i)
#pragma unroll
    for (int j = 0; j < 4; ++j)
      Ts[(eg * 4 + j) * 130 + fg * 8 + i] = acc[i][j];
  __syncthreads();

  const int e = tid >> 2, fs = (tid & 3) * 32;
  size_t orow = ((size_t)b * 512 + h * 64 + e) * 512 + f0 + fs;
#pragma unroll
  for (int c = 0; c < 4; ++c) {
    bf16x8 vh, vl;
#pragma unroll
    for (int j = 0; j < 8; ++j) {
      float v = Ts[e * 130 + fs + c * 8 + j];
      __bf16 hh = (__bf16)v;
      vh[j] = hh;
      vl[j] = (__bf16)(v - (float)hh);
    }
    *(bf16x8*)&WvAt_h[orow + c * 8] = vh;
    *(bf16x8*)&WvAt_l[orow + c * 8] = vl;
  }
}

// ---------------------------------------------------------------------------
// kernel_launch
// ---------------------------------------------------------------------------
extern "C" void kernel_launch(void* const* d_in, const int* in_sizes, int n_in,
                              void* d_out, int out_size, void* d_ws, size_t ws_size,
                              hipStream_t stream) {
  const float* x  = (const float*)d_in[0];
  const float* Wq = (const float*)d_in[1];
  const float* bq = (const float*)d_in[2];
  const float* Wk = (const float*)d_in[3];
  const float* bk = (const float*)d_in[4];
  const float* Wv = (const float*)d_in[5];
  const float* bv = (const float*)d_in[6];
  const float* Wo = (const float*)d_in[7];
  const float* bo = (const float*)d_in[8];
  float* out = (float*)d_out;
  (void)in_sizes; (void)n_in; (void)out_size; (void)ws_size;

  // workspace layout (float units), total ~234 MiB
  float* w = (float*)d_ws;
  size_t off = 0;
  float* Wq_all = w + off; off += 262144;
  float* Wk_all = w + off; off += 262144;
  float* Wv_all = w + off; off += 262144;
  float* s_part = w + off; off += 262144;
  float* pq     = w + off; off += 16384;
  float* pk     = w + off; off += 16384;
  float* U      = w + off; off += (size_t)32 * 262144;      // 32 MiB
  float* Amat   = w + off; off += 1048576;                  // 4 MiB
  float* bvA    = w + off; off += 16384;
  __bf16* Wkt_h = (__bf16*)(w + off); off += 131072;        // 512x512 bf16
  __bf16* Wkt_l = (__bf16*)(w + off); off += 131072;
  __bf16* Wot_h = (__bf16*)(w + off); off += 131072;
  __bf16* Wot_l = (__bf16*)(w + off); off += 131072;
  __bf16* Gh    = (__bf16*)(w + off); off += (size_t)32 * 131072;   // 16 MiB
  __bf16* Gl    = (__bf16*)(w + off); off += (size_t)32 * 131072;
  __bf16* WvAt_h= (__bf16*)(w + off); off += (size_t)32 * 131072;
  __bf16* WvAt_l= (__bf16*)(w + off); off += (size_t)32 * 131072;
  __bf16* Hh    = (__bf16*)(w + off); off += (size_t)131072 * 256;  // 128 MiB

  // 1. pack weights (+ transposed bf16 pairs)
  pack3_kernel<<<1024, 256, 0, stream>>>(Wq, Wk, Wv, Wo, Wq_all, Wk_all, Wv_all,
                                         Wkt_h, Wkt_l, Wot_h, Wot_l);
  // 2. column sums + bias-correction vectors
  colsum_kernel<<<dim3(BATCH, 16), 256, 0, stream>>>(x, s_part);
  pqk_kernel<<<BATCH, 256, 0, stream>>>(s_part, Wq_all, Wk_all, pq, pk);
  // 3. Gram pair: G[b] = x[b]^T x[b]  (both panels F32COL from x)
  mfma_nt<2, 2, 2><<<dim3(4, 4, BATCH), 256, 0, stream>>>(
      x, nullptr, (long long)SEQ * NF, NF,
      x, nullptr, (long long)SEQ * NF, NF,
      nullptr, Gh, Gl, 262144, SEQ);
  // 4. U[b] = G[b] @ Wk_all  (bf16 pairs)
  mfma_nt<0, 0, 0><<<dim3(4, 4, BATCH), 256, 0, stream>>>(
      Gh, Gl, 262144, NF,
      Wkt_h, Wkt_l, 0, NF,
      nullptr, U, nullptr, 262144, NF);
  // 5. scores + softmax -> A, bvA
  score_softmax_kernel<<<256, 256, 0, stream>>>(Wq_all, U, pq, pk, bq, bk, bv,
                                                Amat, bvA);
  // 6. WvA^T pair
  wva_kernel<<<dim3(4, 256), 256, 0, stream>>>(Wv_all, Amat, WvAt_h, WvAt_l);
  // 7. heads: x[b] @ WvAt[b]^T + bvA  -> [h][b][l][e] bf16 (hi only)
  mfma_nt<1, 0, 3><<<dim3(4, 32, BATCH), 256, 0, stream>>>(
      x, nullptr, (long long)SEQ * NF, NF,
      WvAt_h, WvAt_l, 262144, NF,
      bvA, Hh, nullptr, 0, NF);
  // 8. out = Hview @ Wo + bo  (A = Hh only, 2-term)
  mfma_nt<3, 0, 1><<<dim3(4, 1024, 1), 256, 0, stream>>>(
      Hh, nullptr, 0, NF,
      Wot_h, Wot_l, 0, NF,
      bo, out, nullptr, 0, NF);
}

// Round 11
// 1085.332 us; speedup vs baseline: 2.6730x; 1.0898x over previous
//
#include <hip/hip_runtime.h>
#include <hip/hip_bf16.h>
#include <cstdint>
#include <cstddef>

#define BATCH 32
#define SEQ   4096
#define NF    512
#define NH    8
#define HD    64

typedef __bf16 bf16x8 __attribute__((ext_vector_type(8)));
typedef __bf16 bf16x4 __attribute__((ext_vector_type(4)));
typedef float  f32x4  __attribute__((ext_vector_type(4)));

// Blocked LDS layout for MFMA fragments: chunk((mf,kg,r)) = ((mf*4+kg)*16+r),
// 16B per chunk. Verified conflict-free in r9 (SQ_LDS_BANK_CONFLICT = 0).
__device__ __forceinline__ int lds_off(int m, int kg) {
  return (((m >> 4) * 4 + kg) * 16 + (m & 15)) * 8;   // in bf16 units
}

// ---------------------------------------------------------------------------
// Staging modes: 0 = BF16ROW pair, 1 = F32ROW pair (cvt in load phase),
// 2 = F32COL pair (gram's x^T panels), 3 = BF16ROW hi-only, 4 = F32ROW hi-only.
// Split load/store so next tile's global loads overlap current ds_read+MFMA.
// ---------------------------------------------------------------------------
template<int MODE>
struct SRegs { bf16x8 h0, h1, l0, l1; };

__device__ __forceinline__ void cvt8(const float* f, bf16x8& vh, bf16x8& vl) {
#pragma unroll
  for (int j = 0; j < 8; ++j) {
    float x = f[j];
    __bf16 h = (__bf16)x;
    vh[j] = h;
    vl[j] = (__bf16)(x - (float)h);
  }
}

template<int MODE>
__device__ __forceinline__ SRegs<MODE> stage_load(
    const void* pa, const void* pb, long long zoff, int ld,
    long long row0, int k0, int tid)
{
  SRegs<MODE> R;
  if constexpr (MODE == 0 || MODE == 3) {
    const __bf16* hi = (const __bf16*)pa + zoff;
    const int r = tid >> 1, half = tid & 1;
    const size_t base = (size_t)(row0 + r) * ld + k0 + half * 16;
    R.h0 = *(const bf16x8*)(hi + base);
    R.h1 = *(const bf16x8*)(hi + base + 8);
    if constexpr (MODE == 0) {
      const __bf16* lo = (const __bf16*)pb + zoff;
      R.l0 = *(const bf16x8*)(lo + base);
      R.l1 = *(const bf16x8*)(lo + base + 8);
    }
  } else if constexpr (MODE == 1 || MODE == 4) {
    const float* A = (const float*)pa + zoff;
    const int r = tid >> 1, half = tid & 1;
    const float* src = A + (size_t)(row0 + r) * ld + k0 + half * 16;
    float f[16];
#pragma unroll
    for (int q = 0; q < 4; ++q) {
      float4 v = *(const float4*)&src[q * 4];
      f[q * 4 + 0] = v.x; f[q * 4 + 1] = v.y; f[q * 4 + 2] = v.z; f[q * 4 + 3] = v.w;
    }
    if constexpr (MODE == 1) {
      cvt8(f, R.h0, R.l0);
      cvt8(f + 8, R.h1, R.l1);
    } else {
#pragma unroll
      for (int j = 0; j < 8; ++j) {
        R.h0[j] = (__bf16)f[j];
        R.h1[j] = (__bf16)f[8 + j];
      }
    }
  } else {  // MODE 2: F32COL, panel[m][k] = src[k][m]
    const float* A = (const float*)pa + zoff;
    const int m = tid & 127, lg = (tid >> 7) * 16;
    float f[16];
#pragma unroll
    for (int i = 0; i < 16; ++i)
      f[i] = A[(size_t)(k0 + lg + i) * ld + row0 + m];
    cvt8(f, R.h0, R.l0);
    cvt8(f + 8, R.h1, R.l1);
  }
  return R;
}

template<int MODE>
__device__ __forceinline__ void stage_store(
    const SRegs<MODE>& R, __bf16* sH, __bf16* sL, int tid)
{
  if constexpr (MODE == 2) {
    const int m = tid & 127, kq = (tid >> 7) * 2;
    *(bf16x8*)&sH[lds_off(m, kq + 0)] = R.h0;
    *(bf16x8*)&sH[lds_off(m, kq + 1)] = R.h1;
    *(bf16x8*)&sL[lds_off(m, kq + 0)] = R.l0;
    *(bf16x8*)&sL[lds_off(m, kq + 1)] = R.l1;
  } else {
    const int r = tid >> 1, kq = (tid & 1) * 2;
    *(bf16x8*)&sH[lds_off(r, kq + 0)] = R.h0;
    *(bf16x8*)&sH[lds_off(r, kq + 1)] = R.h1;
    if constexpr (MODE == 0 || MODE == 1) {
      *(bf16x8*)&sL[lds_off(r, kq + 0)] = R.l0;
      *(bf16x8*)&sL[lds_off(r, kq + 1)] = R.l1;
    }
  }
}

// ---------------------------------------------------------------------------
// Split-bf16 MFMA NT GEMM: C[z][m][n] = sum_k A[z][m][k] * B[z][n][k]
// 128x128 tile, BK=32, 4 waves 2x2, 4x4 frags of 16x16x32 per wave.
// Terms: Ah*Bh always; + Al*Bh if A staged with lo; + Ah*Bl if B staged with lo.
// EPI: 0 = f32 (U), 1 = f32 + bias[n] (out), 2 = bf16 hi/lo pair (G),
//      3 = heads (bf16 hi only, bvA bias, [h][b][l][e] scatter)
// SYM (gram): grid.x = 10 upper-triangle blocks; off-diagonal blocks also
// write the exact transposed tile (G symmetric) -> 16->10 blocks/batch.
// XCD-chunked block swizzle: consecutive same-XCD blocks share the A panel.
// ---------------------------------------------------------------------------
template<int MA, int MB, int EPI, bool SYM = false>
__global__ __launch_bounds__(256) void mfma_nt(
    const void* Aa, const void* Ab, long long sA, int lda,
    const void* Ba, const void* Bb, long long sB, int ldb,
    const float* __restrict__ bias, void* C0, void* C1, long long sC, int K)
{
  constexpr bool AL = (MA <= 2);
  constexpr bool BL = (MB <= 2);
  constexpr int NBUF = 2 + (AL ? 1 : 0) + (BL ? 1 : 0);
  __shared__ __bf16 smem[NBUF * 4096];
  __bf16* sAh = smem;
  __bf16* sBh = smem + 4096;
  __bf16* sAl = AL ? (smem + 8192) : smem;
  __bf16* sBl = BL ? (smem + (AL ? 12288 : 8192)) : smem;

  const int tid = threadIdx.x;
  const int lane = tid & 63, wave = tid >> 6;
  const int wm = wave >> 1, wn = wave & 1;

  // XCD-chunked swizzle (all grids are multiples of 8)
  const unsigned nx = gridDim.x, ny = gridDim.y;
  const unsigned nwg = nx * ny * gridDim.z;
  unsigned bid = blockIdx.x + nx * (blockIdx.y + ny * blockIdx.z);
  unsigned nid = (bid & 7) * (nwg >> 3) + (bid >> 3);
  const unsigned bx = nid % nx;
  unsigned t = nid / nx;
  const unsigned by = t % ny;
  const unsigned z = t / ny;

  unsigned ti = 0, tj = 0;
  long long m0;
  int n0;
  if constexpr (SYM) {
    if (bx < 4)      { ti = 0; tj = bx; }
    else if (bx < 7) { ti = 1; tj = bx - 3; }
    else if (bx < 9) { ti = 2; tj = bx - 5; }
    else             { ti = 3; tj = 3; }
    m0 = (long long)ti * 128;
    n0 = tj * 128;
  } else {
    m0 = (long long)by * 128;
    n0 = bx * 128;
  }
  const long long zA = (long long)z * sA, zB = (long long)z * sB;

  f32x4 acc[4][4];
#pragma unroll
  for (int i = 0; i < 4; ++i)
#pragma unroll
    for (int j = 0; j < 4; ++j)
#pragma unroll
      for (int c = 0; c < 4; ++c) acc[i][j][c] = 0.f;

  const int kg = lane >> 4, r = lane & 15;

  SRegs<MA> ra = stage_load<MA>(Aa, Ab, zA, lda, m0, 0, tid);
  SRegs<MB> rb = stage_load<MB>(Ba, Bb, zB, ldb, n0, 0, tid);

  for (int k0 = 0; k0 < K; k0 += 32) {
    __syncthreads();   // previous iteration's LDS reads complete
    stage_store<MA>(ra, sAh, sAl, tid);
    stage_store<MB>(rb, sBh, sBl, tid);
    __syncthreads();
    if (k0 + 32 < K) {   // prefetch next tile (overlaps ds_read + MFMA below)
      ra = stage_load<MA>(Aa, Ab, zA, lda, m0, k0 + 32, tid);
      rb = stage_load<MB>(Ba, Bb, zB, ldb, n0, k0 + 32, tid);
    }

    bf16x8 ah[4], al[4], bh[4], bl[4];
#pragma unroll
    for (int i = 0; i < 4; ++i) {
      ah[i] = *(const bf16x8*)&sAh[lds_off(wm * 64 + i * 16 + r, kg)];
      if constexpr (AL)
        al[i] = *(const bf16x8*)&sAl[lds_off(wm * 64 + i * 16 + r, kg)];
      bh[i] = *(const bf16x8*)&sBh[lds_off(wn * 64 + i * 16 + r, kg)];
      if constexpr (BL)
        bl[i] = *(const bf16x8*)&sBl[lds_off(wn * 64 + i * 16 + r, kg)];
    }
#pragma unroll
    for (int i = 0; i < 4; ++i)
#pragma unroll
      for (int j = 0; j < 4; ++j) {
        acc[i][j] = __builtin_amdgcn_mfma_f32_16x16x32_bf16(ah[i], bh[j], acc[i][j], 0, 0, 0);
        if constexpr (AL)
          acc[i][j] = __builtin_amdgcn_mfma_f32_16x16x32_bf16(al[i], bh[j], acc[i][j], 0, 0, 0);
        if constexpr (BL)
          acc[i][j] = __builtin_amdgcn_mfma_f32_16x16x32_bf16(ah[i], bl[j], acc[i][j], 0, 0, 0);
      }
  }

  // Epilogue. C/D layout: col = lane&15, row = (lane>>4)*4 + reg  [m89-verified]
  const int rbase = (lane >> 4) * 4;
  const int cn = lane & 15;
#pragma unroll
  for (int i = 0; i < 4; ++i) {
    const long long gm = m0 + wm * 64 + i * 16 + rbase;
#pragma unroll
    for (int j = 0; j < 4; ++j) {
      const int gn = n0 + wn * 64 + j * 16 + cn;
      if constexpr (EPI == 0) {
        float* C = (float*)C0 + (long long)z * sC;
#pragma unroll
        for (int rr = 0; rr < 4; ++rr)
          C[(size_t)(gm + rr) * 512 + gn] = acc[i][j][rr];
      } else if constexpr (EPI == 1) {
        float* C = (float*)C0;
        const float bv = bias[gn];
#pragma unroll
        for (int rr = 0; rr < 4; ++rr)
          C[(size_t)(gm + rr) * 512 + gn] = acc[i][j][rr] + bv;
      } else if constexpr (EPI == 2) {
        __bf16* Ch = (__bf16*)C0 + (long long)z * sC;
        __bf16* Cl = (__bf16*)C1 + (long long)z * sC;
        bf16x4 th, tl;
#pragma unroll
        for (int rr = 0; rr < 4; ++rr) {
          float v = acc[i][j][rr];
          __bf16 h = (__bf16)v;
          th[rr] = h;
          tl[rr] = (__bf16)(v - (float)h);
          Ch[(size_t)(gm + rr) * 512 + gn] = h;
          Cl[(size_t)(gm + rr) * 512 + gn] = tl[rr];
        }
        if constexpr (SYM) {
          if (ti != tj) {   // exact transposed tile (G symmetric)
            *(bf16x4*)&Ch[(size_t)gn * 512 + gm] = th;
            *(bf16x4*)&Cl[(size_t)gn * 512 + gm] = tl;
          }
        }
      } else {  // heads: col n -> head h, e; row -> [h][b][l] flat; hi only
        const int h = gn >> 6, e = gn & 63;
        const float bv = bias[(h * 32 + (int)z) * 64 + e];
        __bf16* Ch = (__bf16*)C0;
        const size_t rowb = (size_t)(h * 32 + (int)z) * 4096 + gm;
#pragma unroll
        for (int rr = 0; rr < 4; ++rr)
          Ch[(rowb + rr) * 64 + e] = (__bf16)(acc[i][j][rr] + bv);
      }
    }
  }
}

// ---------------------------------------------------------------------------
// Pack W{q,k,v} [H][F][D] -> [F][512] fp32; Wk^T as bf16 hi/lo; Wo^T bf16 hi.
// ---------------------------------------------------------------------------
__global__ void pack3_kernel(const float* __restrict__ Wq, const float* __restrict__ Wk,
                             const float* __restrict__ Wv, const float* __restrict__ Wo,
                             float* __restrict__ Wq_all, float* __restrict__ Wk_all,
                             float* __restrict__ Wv_all,
                             __bf16* __restrict__ Wkt_h, __bf16* __restrict__ Wkt_l,
                             __bf16* __restrict__ Wot_h) {
  int i = blockIdx.x * 256 + threadIdx.x;
  if (i >= NF * NF) return;
  int f = i >> 9, n = i & 511, h = n >> 6, d = n & 63;
  size_t src = ((size_t)h * NF + f) * HD + d;
  float wq = Wq[src], wk = Wk[src], wv = Wv[src];
  Wq_all[i] = wq;
  Wk_all[i] = wk;
  Wv_all[i] = wv;
  __bf16 kh = (__bf16)wk;
  Wkt_h[(size_t)n * 512 + f] = kh;
  Wkt_l[(size_t)n * 512 + f] = (__bf16)(wk - (float)kh);
  Wot_h[(size_t)n * 512 + f] = (__bf16)Wo[i];   // Wo[f][n] transposed, hi only
}

// ---------------------------------------------------------------------------
// Column sums of x (two-stage) + p_q/p_k = s @ W (bias-correction vectors).
// ---------------------------------------------------------------------------
__global__ __launch_bounds__(256) void colsum_kernel(const float* __restrict__ x,
                                                     float* __restrict__ s_part) {
  const int b = blockIdx.x, c = blockIdx.y, t = threadIdx.x;
  const float* base = x + ((size_t)b * SEQ + c * 256) * NF;
  float a0 = 0.f, a1 = 0.f;
  for (int l = 0; l < 256; ++l) {
    a0 += base[(size_t)l * NF + t];
    a1 += base[(size_t)l * NF + t + 256];
  }
  float* o = s_part + ((size_t)b * 16 + c) * NF;
  o[t] = a0;
  o[t + 256] = a1;
}

__global__ __launch_bounds__(256) void pqk_kernel(
    const float* __restrict__ s_part, const float* __restrict__ Wq_all,
    const float* __restrict__ Wk_all, float* __restrict__ pq, float* __restrict__ pk) {
  const int b = blockIdx.x, t = threadIdx.x;
  __shared__ float s[512];
  float a0 = 0.f, a1 = 0.f;
  for (int c = 0; c < 16; ++c) {
    a0 += s_part[((size_t)b * 16 + c) * NF + t];
    a1 += s_part[((size_t)b * 16 + c) * NF + t + 256];
  }
  s[t] = a0;
  s[t + 256] = a1;
  __syncthreads();
  float q0 = 0.f, q1 = 0.f, k0 = 0.f, k1 = 0.f;
  for (int f = 0; f < NF; ++f) {
    const float sv = s[f];
    q0 += sv * Wq_all[(size_t)f * NF + t];
    q1 += sv * Wq_all[(size_t)f * NF + t + 256];
    k0 += sv * Wk_all[(size_t)f * NF + t];
    k1 += sv * Wk_all[(size_t)f * NF + t + 256];
  }
  pq[(size_t)b * NF + t] = q0;
  pq[(size_t)b * NF + t + 256] = q1;
  pk[(size_t)b * NF + t] = k0;
  pk[(size_t)b * NF + t + 256] = k1;
}

// ---------------------------------------------------------------------------
// Scores + softmax per (h,b) -> A[hb][64][64], bvA[hb][64]  (fp32).
// Softmax parallelized across all 256 lanes: 4 d-quarters x 64 e-columns.
// ---------------------------------------------------------------------------
__global__ __launch_bounds__(256) void score_softmax_kernel(
    const float* __restrict__ Wq_all, const float* __restrict__ U,
    const float* __restrict__ pq, const float* __restrict__ pk,
    const float* __restrict__ bq, const float* __restrict__ bk,
    const float* __restrict__ bv,
    float* __restrict__ Amat, float* __restrict__ bvA) {
  const int hb = blockIdx.x;
  const int h = hb >> 5, b = hb & 31;
  __shared__ float Qs[64][65];
  __shared__ float Us[64][65];
  __shared__ float Ss[64][65];
  __shared__ float red[4][64];
  const int tid = threadIdx.x, eg = tid & 15, dg = tid >> 4;
  const float* Ub = U + (size_t)b * NF * NF;

  float acc[4][4];
#pragma unroll
  for (int i = 0; i < 4; ++i)
#pragma unroll
    for (int j = 0; j < 4; ++j) acc[i][j] = 0.f;

  for (int f0 = 0; f0 < NF; f0 += 64) {
#pragma unroll
    for (int q = 0; q < 4; ++q) {
      const int idx = q * 256 + tid;
      const int fi = idx >> 4, dd = (idx & 15) * 4;
      *(float4*)&Qs[fi][dd] = *(const float4*)&Wq_all[(size_t)(f0 + fi) * NF + h * HD + dd];
      *(float4*)&Us[fi][dd] = *(const float4*)&Ub[(size_t)(f0 + fi) * NF + h * HD + dd];
    }
    __syncthreads();
#pragma unroll 16
    for (int fi = 0; fi < 64; ++fi) {
      float4 qa = *(float4*)&Qs[fi][dg * 4];
      float4 ub = *(float4*)&Us[fi][eg * 4];
      float qa_[4] = {qa.x, qa.y, qa.z, qa.w};
      float ub_[4] = {ub.x, ub.y, ub.z, ub.w};
#pragma unroll
      for (int i = 0; i < 4; ++i)
#pragma unroll
        for (int j = 0; j < 4; ++j) acc[i][j] = fmaf(qa_[i], ub_[j], acc[i][j]);
    }
    __syncthreads();
  }

#pragma unroll
  for (int i = 0; i < 4; ++i) {
    const int d = dg * 4 + i;
    const float bqv = bq[h * HD + d];
    const float pqv = pq[(size_t)b * NF + h * HD + d];
#pragma unroll
    for (int j = 0; j < 4; ++j) {
      const int e = eg * 4 + j;
      const float bkv = bk[h * HD + e];
      const float pkv = pk[(size_t)b * NF + h * HD + e];
      float v = acc[i][j] + bqv * pkv + bkv * pqv + 4096.f * bqv * bkv;
      Ss[d][e] = v * 0.125f;
    }
  }
  __syncthreads();

  // wave-parallel softmax over d (rows) per column e: 4 quarters x 64 cols
  const int e = tid & 63, q = tid >> 6;
  float pm = -INFINITY;
#pragma unroll
  for (int d = 0; d < 16; ++d) pm = fmaxf(pm, Ss[q * 16 + d][e]);
  red[q][e] = pm;
  __syncthreads();
  const float m = fmaxf(fmaxf(red[0][e], red[1][e]), fmaxf(red[2][e], red[3][e]));
  __syncthreads();
  float ps = 0.f;
#pragma unroll
  for (int d = 0; d < 16; ++d) {
    float ex = __expf(Ss[q * 16 + d][e] - m);
    Ss[q * 16 + d][e] = ex;
    ps += ex;
  }
  red[q][e] = ps;
  __syncthreads();
  const float inv = 1.f / (red[0][e] + red[1][e] + red[2][e] + red[3][e]);
  __syncthreads();
  float bacc = 0.f;
#pragma unroll
  for (int d = 0; d < 16; ++d) {
    const int dd = q * 16 + d;
    const float a = Ss[dd][e] * inv;
    Amat[(size_t)hb * 4096 + dd * 64 + e] = a;
    bacc = fmaf(bv[h * HD + dd], a, bacc);
  }
  red[q][e] = bacc;
  __syncthreads();
  if (tid < 64)
    bvA[(size_t)hb * HD + tid] = red[0][tid] + red[1][tid] + red[2][tid] + red[3][tid];
}

// ---------------------------------------------------------------------------
// WvA^T[b][n=h*64+e][f] (bf16 hi only) = sum_d Wv_all[f][h*64+d] * A[hb][d][e]
// ---------------------------------------------------------------------------
__global__ __launch_bounds__(256) void wva_kernel(
    const float* __restrict__ Wv_all, const float* __restrict__ Amat,
    __bf16* __restrict__ WvAt_h) {
  const int hb = blockIdx.y, h = hb >> 5, b = hb & 31;
  const int f0 = blockIdx.x * 128;
  __shared__ float Ws[128][65];
  __shared__ float As[64][65];
  const int tid = threadIdx.x;

#pragma unroll
  for (int q = 0; q < 4; ++q) {
    const int idx = q * 256 + tid;
    const int d = idx >> 4, ee = (idx & 15) * 4;
    *(float4*)&As[d][ee] = *(const float4*)&Amat[(size_t)hb * 4096 + d * 64 + ee];
  }
#pragma unroll
  for (int q = 0; q < 8; ++q) {
    const int idx = q * 256 + tid;
    const int fi = idx >> 4, dd = (idx & 15) * 4;
    *(float4*)&Ws[fi][dd] = *(const float4*)&Wv_all[(size_t)(f0 + fi) * NF + h * HD + dd];
  }
  __syncthreads();

  const int fg = tid >> 4, eg = tid & 15;
  float acc[8][4];
#pragma unroll
  for (int i = 0; i < 8; ++i)
#pragma unroll
    for (int j = 0; j < 4; ++j) acc[i][j] = 0.f;
#pragma unroll 8
  for (int d = 0; d < 64; ++d) {
    float4 av = *(float4*)&As[d][eg * 4];
    float a_[4] = {av.x, av.y, av.z, av.w};
#pragma unroll
    for (int i = 0; i < 8; ++i) {
      const float w = Ws[fg * 8 + i][d];
#pragma unroll
      for (int j = 0; j < 4; ++j) acc[i][j] = fmaf(w, a_[j], acc[i][j]);
    }
  }

  // transpose via LDS (reuse Ws as [64][130]) then coalesced bf16 store
  __syncthreads();
  float* Ts = &Ws[0][0];
#pragma unroll
  for (int i = 0; i < 8; ++i)
#pragma unroll
    for (int j = 0; j < 4; ++j)
      Ts[(eg * 4 + j) * 130 + fg * 8 + i] = acc[i][j];
  __syncthreads();

  const int e = tid >> 2, fs = (tid & 3) * 32;
  size_t orow = ((size_t)b * 512 + h * 64 + e) * 512 + f0 + fs;
#pragma unroll
  for (int c = 0; c < 4; ++c) {
    bf16x8 vh;
#pragma unroll
    for (int j = 0; j < 8; ++j)
      vh[j] = (__bf16)Ts[e * 130 + fs + c * 8 + j];
    *(bf16x8*)&WvAt_h[orow + c * 8] = vh;
  }
}

// ---------------------------------------------------------------------------
// kernel_launch
// ---------------------------------------------------------------------------
extern "C" void kernel_launch(void* const* d_in, const int* in_sizes, int n_in,
                              void* d_out, int out_size, void* d_ws, size_t ws_size,
                              hipStream_t stream) {
  const float* x  = (const float*)d_in[0];
  const float* Wq = (const float*)d_in[1];
  const float* bq = (const float*)d_in[2];
  const float* Wk = (const float*)d_in[3];
  const float* bk = (const float*)d_in[4];
  const float* Wv = (const float*)d_in[5];
  const float* bv = (const float*)d_in[6];
  const float* Wo = (const float*)d_in[7];
  const float* bo = (const float*)d_in[8];
  float* out = (float*)d_out;
  (void)in_sizes; (void)n_in; (void)out_size; (void)ws_size;

  // workspace layout (float units), total ~200 MiB
  float* w = (float*)d_ws;
  size_t off = 0;
  float* Wq_all = w + off; off += 262144;
  float* Wk_all = w + off; off += 262144;
  float* Wv_all = w + off; off += 262144;
  float* s_part = w + off; off += 262144;
  float* pq     = w + off; off += 16384;
  float* pk     = w + off; off += 16384;
  float* U      = w + off; off += (size_t)32 * 262144;      // 32 MiB
  float* Amat   = w + off; off += 1048576;                  // 4 MiB
  float* bvA    = w + off; off += 16384;
  __bf16* Wkt_h = (__bf16*)(w + off); off += 131072;        // 512x512 bf16
  __bf16* Wkt_l = (__bf16*)(w + off); off += 131072;
  __bf16* Wot_h = (__bf16*)(w + off); off += 131072;
  __bf16* Gh    = (__bf16*)(w + off); off += (size_t)32 * 131072;   // 16 MiB
  __bf16* Gl    = (__bf16*)(w + off); off += (size_t)32 * 131072;
  __bf16* WvAt_h= (__bf16*)(w + off); off += (size_t)32 * 131072;
  __bf16* Hh    = (__bf16*)(w + off); off += (size_t)131072 * 256;  // 128 MiB

  // 1. pack weights
  pack3_kernel<<<1024, 256, 0, stream>>>(Wq, Wk, Wv, Wo, Wq_all, Wk_all, Wv_all,
                                         Wkt_h, Wkt_l, Wot_h);
  // 2. column sums + bias-correction vectors
  colsum_kernel<<<dim3(BATCH, 16), 256, 0, stream>>>(x, s_part);
  pqk_kernel<<<BATCH, 256, 0, stream>>>(s_part, Wq_all, Wk_all, pq, pk);
  // 3. Gram pair (3-term, symmetric: 10 upper-triangle blocks/batch)
  mfma_nt<2, 2, 2, true><<<dim3(10, 1, BATCH), 256, 0, stream>>>(
      x, nullptr, (long long)SEQ * NF, NF,
      x, nullptr, (long long)SEQ * NF, NF,
      nullptr, Gh, Gl, 262144, SEQ);
  // 4. U[b] = G[b] @ Wk_all  (3-term, bf16 pairs)
  mfma_nt<0, 0, 0><<<dim3(4, 4, BATCH), 256, 0, stream>>>(
      Gh, Gl, 262144, NF,
      Wkt_h, Wkt_l, 0, NF,
      nullptr, U, nullptr, 262144, NF);
  // 5. scores + softmax -> A, bvA
  score_softmax_kernel<<<256, 256, 0, stream>>>(Wq_all, U, pq, pk, bq, bk, bv,
                                                Amat, bvA);
  // 6. WvA^T (bf16 hi only)
  wva_kernel<<<dim3(4, 256), 256, 0, stream>>>(Wv_all, Amat, WvAt_h);
  // 7. heads: x[b] @ WvAt[b]^T + bvA -> [h][b][l][e] bf16 (1-term pure bf16)
  mfma_nt<4, 3, 3><<<dim3(4, 32, BATCH), 256, 0, stream>>>(
      x, nullptr, (long long)SEQ * NF, NF,
      WvAt_h, nullptr, 262144, NF,
      bvA, Hh, nullptr, 0, NF);
  // 8. out = Hview @ Wo + bo  (1-term pure bf16)
  mfma_nt<3, 3, 1><<<dim3(4, 1024, 1), 256, 0, stream>>>(
      Hh, nullptr, 0, NF,
      Wot_h, nullptr, 0, NF,
      bo, out, nullptr, 0, NF);
}

// Round 12
// 1046.722 us; speedup vs baseline: 2.7716x; 1.0369x over previous
//
#include <hip/hip_runtime.h>
#include <hip/hip_bf16.h>
#include <cstdint>
#include <cstddef>

#define BATCH 32
#define SEQ   4096
#define NF    512
#define NH    8
#define HD    64

typedef __bf16 bf16x8 __attribute__((ext_vector_type(8)));
typedef __bf16 bf16x4 __attribute__((ext_vector_type(4)));
typedef float  f32x4  __attribute__((ext_vector_type(4)));

// Blocked LDS layout for MFMA fragments: chunk((mf,kg,r)) = ((mf*4+kg)*16+r),
// 16B per chunk. Verified conflict-free in r9 (SQ_LDS_BANK_CONFLICT = 0).
__device__ __forceinline__ int lds_off(int m, int kg) {
  return (((m >> 4) * 4 + kg) * 16 + (m & 15)) * 8;   // in bf16 units
}

// ---------------------------------------------------------------------------
// Staging modes: 0 = BF16ROW pair, 1 = F32ROW pair (cvt in load phase),
// 2 = F32COL pair (gram's x^T panels), 3 = BF16ROW hi-only, 4 = F32ROW hi-only.
// Split load/store so next tile's global loads overlap current ds_read+MFMA.
// ---------------------------------------------------------------------------
template<int MODE>
struct SRegs { bf16x8 h0, h1, l0, l1; };

__device__ __forceinline__ void cvt8(const float* f, bf16x8& vh, bf16x8& vl) {
#pragma unroll
  for (int j = 0; j < 8; ++j) {
    float x = f[j];
    __bf16 h = (__bf16)x;
    vh[j] = h;
    vl[j] = (__bf16)(x - (float)h);
  }
}

template<int MODE>
__device__ __forceinline__ SRegs<MODE> stage_load(
    const void* pa, const void* pb, long long zoff, int ld,
    long long row0, int k0, int tid)
{
  SRegs<MODE> R;
  if constexpr (MODE == 0 || MODE == 3) {
    const __bf16* hi = (const __bf16*)pa + zoff;
    const int r = tid >> 1, half = tid & 1;
    const size_t base = (size_t)(row0 + r) * ld + k0 + half * 16;
    R.h0 = *(const bf16x8*)(hi + base);
    R.h1 = *(const bf16x8*)(hi + base + 8);
    if constexpr (MODE == 0) {
      const __bf16* lo = (const __bf16*)pb + zoff;
      R.l0 = *(const bf16x8*)(lo + base);
      R.l1 = *(const bf16x8*)(lo + base + 8);
    }
  } else if constexpr (MODE == 1 || MODE == 4) {
    const float* A = (const float*)pa + zoff;
    const int r = tid >> 1, half = tid & 1;
    const float* src = A + (size_t)(row0 + r) * ld + k0 + half * 16;
    float f[16];
#pragma unroll
    for (int q = 0; q < 4; ++q) {
      float4 v = *(const float4*)&src[q * 4];
      f[q * 4 + 0] = v.x; f[q * 4 + 1] = v.y; f[q * 4 + 2] = v.z; f[q * 4 + 3] = v.w;
    }
    if constexpr (MODE == 1) {
      cvt8(f, R.h0, R.l0);
      cvt8(f + 8, R.h1, R.l1);
    } else {
#pragma unroll
      for (int j = 0; j < 8; ++j) {
        R.h0[j] = (__bf16)f[j];
        R.h1[j] = (__bf16)f[8 + j];
      }
    }
  } else {  // MODE 2: F32COL, panel[m][k] = src[k][m]
    const float* A = (const float*)pa + zoff;
    const int m = tid & 127, lg = (tid >> 7) * 16;
    float f[16];
#pragma unroll
    for (int i = 0; i < 16; ++i)
      f[i] = A[(size_t)(k0 + lg + i) * ld + row0 + m];
    cvt8(f, R.h0, R.l0);
    cvt8(f + 8, R.h1, R.l1);
  }
  return R;
}

template<int MODE>
__device__ __forceinline__ void stage_store(
    const SRegs<MODE>& R, __bf16* sH, __bf16* sL, int tid)
{
  if constexpr (MODE == 2) {
    const int m = tid & 127, kq = (tid >> 7) * 2;
    *(bf16x8*)&sH[lds_off(m, kq + 0)] = R.h0;
    *(bf16x8*)&sH[lds_off(m, kq + 1)] = R.h1;
    *(bf16x8*)&sL[lds_off(m, kq + 0)] = R.l0;
    *(bf16x8*)&sL[lds_off(m, kq + 1)] = R.l1;
  } else {
    const int r = tid >> 1, kq = (tid & 1) * 2;
    *(bf16x8*)&sH[lds_off(r, kq + 0)] = R.h0;
    *(bf16x8*)&sH[lds_off(r, kq + 1)] = R.h1;
    if constexpr (MODE == 0 || MODE == 1) {
      *(bf16x8*)&sL[lds_off(r, kq + 0)] = R.l0;
      *(bf16x8*)&sL[lds_off(r, kq + 1)] = R.l1;
    }
  }
}

// ---------------------------------------------------------------------------
// Split-bf16 MFMA NT GEMM: C[z][m][n] = sum_k A[z][m][k] * B[z][n][k]
// 128x128 tile, BK=32, 4 waves 2x2, 4x4 frags of 16x16x32 per wave.
// Terms: Ah*Bh always; + Al*Bh if A staged with lo; + Ah*Bl if B staged with lo.
// EPI: 0 = f32 (U), 1 = f32 + bias[n] (out),
//      3 = heads (bf16 hi only, bvA bias, [h][b][l][e] scatter),
//      4 = fp32 compact partial tile (gram split-K)
// SYM (gram split-K): bx = upper-triangle tile (10), by = K-chunk (4).
// 1280 blocks -> 5 blocks/CU (r11's 320-block version was latency-starved:
// 560 TF issued vs 841 at 2 blocks/CU — occupancy 12.5%, MfmaUtil 24).
// XCD-chunked block swizzle: consecutive same-XCD blocks share the A panel.
// ---------------------------------------------------------------------------
template<int MA, int MB, int EPI, bool SYM = false>
__global__ __launch_bounds__(256) void mfma_nt(
    const void* Aa, const void* Ab, long long sA, int lda,
    const void* Ba, const void* Bb, long long sB, int ldb,
    const float* __restrict__ bias, void* C0, void* C1, long long sC, int K)
{
  constexpr bool AL = (MA <= 2);
  constexpr bool BL = (MB <= 2);
  constexpr int NBUF = 2 + (AL ? 1 : 0) + (BL ? 1 : 0);
  __shared__ __bf16 smem[NBUF * 4096];
  __bf16* sAh = smem;
  __bf16* sBh = smem + 4096;
  __bf16* sAl = AL ? (smem + 8192) : smem;
  __bf16* sBl = BL ? (smem + (AL ? 12288 : 8192)) : smem;

  const int tid = threadIdx.x;
  const int lane = tid & 63, wave = tid >> 6;
  const int wm = wave >> 1, wn = wave & 1;

  // XCD-chunked swizzle (all grids are multiples of 8)
  const unsigned nx = gridDim.x, ny = gridDim.y;
  const unsigned nwg = nx * ny * gridDim.z;
  unsigned bid = blockIdx.x + nx * (blockIdx.y + ny * blockIdx.z);
  unsigned nid = (bid & 7) * (nwg >> 3) + (bid >> 3);
  const unsigned bx = nid % nx;
  unsigned t = nid / nx;
  const unsigned by = t % ny;
  const unsigned z = t / ny;

  unsigned ti = 0, tj = 0;
  long long m0;
  int n0;
  int kbase = 0;
  if constexpr (SYM) {
    if (bx < 4)      { ti = 0; tj = bx; }
    else if (bx < 7) { ti = 1; tj = bx - 3; }
    else if (bx < 9) { ti = 2; tj = bx - 5; }
    else             { ti = 3; tj = 3; }
    m0 = (long long)ti * 128;
    n0 = tj * 128;
    kbase = (int)by * K;       // by = K-chunk index
  } else {
    m0 = (long long)by * 128;
    n0 = bx * 128;
  }
  const long long zA = (long long)z * sA, zB = (long long)z * sB;

  f32x4 acc[4][4];
#pragma unroll
  for (int i = 0; i < 4; ++i)
#pragma unroll
    for (int j = 0; j < 4; ++j)
#pragma unroll
      for (int c = 0; c < 4; ++c) acc[i][j][c] = 0.f;

  const int kg = lane >> 4, r = lane & 15;

  SRegs<MA> ra = stage_load<MA>(Aa, Ab, zA, lda, m0, kbase, tid);
  SRegs<MB> rb = stage_load<MB>(Ba, Bb, zB, ldb, n0, kbase, tid);

  const int kend = kbase + K;
  for (int k0 = kbase; k0 < kend; k0 += 32) {
    __syncthreads();   // previous iteration's LDS reads complete
    stage_store<MA>(ra, sAh, sAl, tid);
    stage_store<MB>(rb, sBh, sBl, tid);
    __syncthreads();
    if (k0 + 32 < kend) {  // prefetch next tile (overlaps ds_read + MFMA below)
      ra = stage_load<MA>(Aa, Ab, zA, lda, m0, k0 + 32, tid);
      rb = stage_load<MB>(Ba, Bb, zB, ldb, n0, k0 + 32, tid);
    }

    bf16x8 ah[4], al[4], bh[4], bl[4];
#pragma unroll
    for (int i = 0; i < 4; ++i) {
      ah[i] = *(const bf16x8*)&sAh[lds_off(wm * 64 + i * 16 + r, kg)];
      if constexpr (AL)
        al[i] = *(const bf16x8*)&sAl[lds_off(wm * 64 + i * 16 + r, kg)];
      bh[i] = *(const bf16x8*)&sBh[lds_off(wn * 64 + i * 16 + r, kg)];
      if constexpr (BL)
        bl[i] = *(const bf16x8*)&sBl[lds_off(wn * 64 + i * 16 + r, kg)];
    }
#pragma unroll
    for (int i = 0; i < 4; ++i)
#pragma unroll
      for (int j = 0; j < 4; ++j) {
        acc[i][j] = __builtin_amdgcn_mfma_f32_16x16x32_bf16(ah[i], bh[j], acc[i][j], 0, 0, 0);
        if constexpr (AL)
          acc[i][j] = __builtin_amdgcn_mfma_f32_16x16x32_bf16(al[i], bh[j], acc[i][j], 0, 0, 0);
        if constexpr (BL)
          acc[i][j] = __builtin_amdgcn_mfma_f32_16x16x32_bf16(ah[i], bl[j], acc[i][j], 0, 0, 0);
      }
  }

  // Epilogue. C/D layout: col = lane&15, row = (lane>>4)*4 + reg  [m89-verified]
  const int rbase = (lane >> 4) * 4;
  const int cn = lane & 15;
#pragma unroll
  for (int i = 0; i < 4; ++i) {
    const long long gm = m0 + wm * 64 + i * 16 + rbase;
    const int lm = wm * 64 + i * 16 + rbase;
#pragma unroll
    for (int j = 0; j < 4; ++j) {
      const int gn = n0 + wn * 64 + j * 16 + cn;
      const int ln = wn * 64 + j * 16 + cn;
      if constexpr (EPI == 0) {
        float* C = (float*)C0 + (long long)z * sC;
#pragma unroll
        for (int rr = 0; rr < 4; ++rr)
          C[(size_t)(gm + rr) * 512 + gn] = acc[i][j][rr];
      } else if constexpr (EPI == 1) {
        float* C = (float*)C0;
        const float bv = bias[gn];
#pragma unroll
        for (int rr = 0; rr < 4; ++rr)
          C[(size_t)(gm + rr) * 512 + gn] = acc[i][j][rr] + bv;
      } else if constexpr (EPI == 3) {
        // heads: col n -> head h, e; row -> [h][b][l] flat; hi only
        const int h = gn >> 6, e = gn & 63;
        const float bv = bias[(h * 32 + (int)z) * 64 + e];
        __bf16* Ch = (__bf16*)C0;
        const size_t rowb = (size_t)(h * 32 + (int)z) * 4096 + gm;
#pragma unroll
        for (int rr = 0; rr < 4; ++rr)
          Ch[(rowb + rr) * 64 + e] = (__bf16)(acc[i][j][rr] + bv);
      } else {  // EPI == 4: fp32 compact partial tile Gp[kc][z][tile][128][128]
        float* C = (float*)C0 + ((((long long)by * 32 + z) * 10 + bx) * 16384);
#pragma unroll
        for (int rr = 0; rr < 4; ++rr)
          C[(size_t)(lm + rr) * 128 + ln] = acc[i][j][rr];
      }
    }
  }
}

// ---------------------------------------------------------------------------
// Gram reduce: G[z] tile = sum of 4 K-chunk partials; emit bf16 hi/lo at
// (ti,tj) and the exact transposed tile at (tj,ti). LDS transpose keeps both
// write orientations coalesced. grid (10, 32).
// ---------------------------------------------------------------------------
__global__ __launch_bounds__(256) void greduce_kernel(
    const float* __restrict__ Gp, __bf16* __restrict__ Gh,
    __bf16* __restrict__ Gl) {
  const int t = blockIdx.x, z = blockIdx.y;
  const int tid = threadIdx.x;
  __shared__ float T[128][129];
  int ti, tj;
  if (t < 4)      { ti = 0; tj = t; }
  else if (t < 7) { ti = 1; tj = t - 3; }
  else if (t < 9) { ti = 2; tj = t - 5; }
  else            { ti = 3; tj = 3; }
  const size_t base = ((size_t)z * 10 + t) * 16384;
  const size_t cstep = (size_t)32 * 10 * 16384;
#pragma unroll 4
  for (int i = 0; i < 64; ++i) {
    const int idx = i * 256 + tid;
    float v = Gp[base + idx] + Gp[base + cstep + idx]
            + Gp[base + 2 * cstep + idx] + Gp[base + 3 * cstep + idx];
    T[idx >> 7][idx & 127] = v;
  }
  __syncthreads();
  __bf16* GhZ = Gh + (size_t)z * 262144;
  __bf16* GlZ = Gl + (size_t)z * 262144;
#pragma unroll 4
  for (int i = 0; i < 64; ++i) {
    const int idx = i * 256 + tid;
    const int lm = idx >> 7, ln = idx & 127;
    const float v = T[lm][ln];
    const __bf16 h = (__bf16)v;
    GhZ[(size_t)(ti * 128 + lm) * 512 + tj * 128 + ln] = h;
    GlZ[(size_t)(ti * 128 + lm) * 512 + tj * 128 + ln] = (__bf16)(v - (float)h);
  }
  if (ti != tj) {
#pragma unroll 4
    for (int i = 0; i < 64; ++i) {
      const int idx = i * 256 + tid;
      const int q = idx >> 7, p = idx & 127;   // p fastest -> coalesced
      const float v = T[p][q];
      const __bf16 h = (__bf16)v;
      GhZ[(size_t)(tj * 128 + q) * 512 + ti * 128 + p] = h;
      GlZ[(size_t)(tj * 128 + q) * 512 + ti * 128 + p] = (__bf16)(v - (float)h);
    }
  }
}

// ---------------------------------------------------------------------------
// Pack W{q,k,v} [H][F][D] -> [F][512] fp32; Wk^T as bf16 hi/lo; Wo^T bf16 hi.
// ---------------------------------------------------------------------------
__global__ void pack3_kernel(const float* __restrict__ Wq, const float* __restrict__ Wk,
                             const float* __restrict__ Wv, const float* __restrict__ Wo,
                             float* __restrict__ Wq_all, float* __restrict__ Wk_all,
                             float* __restrict__ Wv_all,
                             __bf16* __restrict__ Wkt_h, __bf16* __restrict__ Wkt_l,
                             __bf16* __restrict__ Wot_h) {
  int i = blockIdx.x * 256 + threadIdx.x;
  if (i >= NF * NF) return;
  int f = i >> 9, n = i & 511, h = n >> 6, d = n & 63;
  size_t src = ((size_t)h * NF + f) * HD + d;
  float wq = Wq[src], wk = Wk[src], wv = Wv[src];
  Wq_all[i] = wq;
  Wk_all[i] = wk;
  Wv_all[i] = wv;
  __bf16 kh = (__bf16)wk;
  Wkt_h[(size_t)n * 512 + f] = kh;
  Wkt_l[(size_t)n * 512 + f] = (__bf16)(wk - (float)kh);
  Wot_h[(size_t)n * 512 + f] = (__bf16)Wo[i];   // Wo[f][n] transposed, hi only
}

// ---------------------------------------------------------------------------
// Column sums of x (two-stage) + p_q/p_k = s @ W (bias-correction vectors).
// colsum: 64-row chunks -> 2048 blocks (r11's 512 was latency-starved).
// ---------------------------------------------------------------------------
__global__ __launch_bounds__(256) void colsum_kernel(const float* __restrict__ x,
                                                     float* __restrict__ s_part) {
  const int b = blockIdx.x, c = blockIdx.y, t = threadIdx.x;
  const float* base = x + ((size_t)b * SEQ + c * 64) * NF;
  float a0 = 0.f, a1 = 0.f;
  for (int l = 0; l < 64; ++l) {
    a0 += base[(size_t)l * NF + t];
    a1 += base[(size_t)l * NF + t + 256];
  }
  float* o = s_part + ((size_t)b * 64 + c) * NF;
  o[t] = a0;
  o[t + 256] = a1;
}

__global__ __launch_bounds__(256) void pqk_kernel(
    const float* __restrict__ s_part, const float* __restrict__ Wq_all,
    const float* __restrict__ Wk_all, float* __restrict__ pq, float* __restrict__ pk) {
  const int b = blockIdx.x, t = threadIdx.x;
  __shared__ float s[512];
  float a0 = 0.f, a1 = 0.f;
  for (int c = 0; c < 64; ++c) {
    a0 += s_part[((size_t)b * 64 + c) * NF + t];
    a1 += s_part[((size_t)b * 64 + c) * NF + t + 256];
  }
  s[t] = a0;
  s[t + 256] = a1;
  __syncthreads();
  float q0 = 0.f, q1 = 0.f, k0 = 0.f, k1 = 0.f;
  for (int f = 0; f < NF; ++f) {
    const float sv = s[f];
    q0 += sv * Wq_all[(size_t)f * NF + t];
    q1 += sv * Wq_all[(size_t)f * NF + t + 256];
    k0 += sv * Wk_all[(size_t)f * NF + t];
    k1 += sv * Wk_all[(size_t)f * NF + t + 256];
  }
  pq[(size_t)b * NF + t] = q0;
  pq[(size_t)b * NF + t + 256] = q1;
  pk[(size_t)b * NF + t] = k0;
  pk[(size_t)b * NF + t + 256] = k1;
}

// ---------------------------------------------------------------------------
// Scores + softmax per (h,b) -> A[hb][64][64], bvA[hb][64]  (fp32).
// Softmax parallelized across all 256 lanes: 4 d-quarters x 64 e-columns.
// ---------------------------------------------------------------------------
__global__ __launch_bounds__(256) void score_softmax_kernel(
    const float* __restrict__ Wq_all, const float* __restrict__ U,
    const float* __restrict__ pq, const float* __restrict__ pk,
    const float* __restrict__ bq, const float* __restrict__ bk,
    const float* __restrict__ bv,
    float* __restrict__ Amat, float* __restrict__ bvA) {
  const int hb = blockIdx.x;
  const int h = hb >> 5, b = hb & 31;
  __shared__ float Qs[64][65];
  __shared__ float Us[64][65];
  __shared__ float Ss[64][65];
  __shared__ float red[4][64];
  const int tid = threadIdx.x, eg = tid & 15, dg = tid >> 4;
  const float* Ub = U + (size_t)b * NF * NF;

  float acc[4][4];
#pragma unroll
  for (int i = 0; i < 4; ++i)
#pragma unroll
    for (int j = 0; j < 4; ++j) acc[i][j] = 0.f;

  for (int f0 = 0; f0 < NF; f0 += 64) {
#pragma unroll
    for (int q = 0; q < 4; ++q) {
      const int idx = q * 256 + tid;
      const int fi = idx >> 4, dd = (idx & 15) * 4;
      *(float4*)&Qs[fi][dd] = *(const float4*)&Wq_all[(size_t)(f0 + fi) * NF + h * HD + dd];
      *(float4*)&Us[fi][dd] = *(const float4*)&Ub[(size_t)(f0 + fi) * NF + h * HD + dd];
    }
    __syncthreads();
#pragma unroll 16
    for (int fi = 0; fi < 64; ++fi) {
      float4 qa = *(float4*)&Qs[fi][dg * 4];
      float4 ub = *(float4*)&Us[fi][eg * 4];
      float qa_[4] = {qa.x, qa.y, qa.z, qa.w};
      float ub_[4] = {ub.x, ub.y, ub.z, ub.w};
#pragma unroll
      for (int i = 0; i < 4; ++i)
#pragma unroll
        for (int j = 0; j < 4; ++j) acc[i][j] = fmaf(qa_[i], ub_[j], acc[i][j]);
    }
    __syncthreads();
  }

#pragma unroll
  for (int i = 0; i < 4; ++i) {
    const int d = dg * 4 + i;
    const float bqv = bq[h * HD + d];
    const float pqv = pq[(size_t)b * NF + h * HD + d];
#pragma unroll
    for (int j = 0; j < 4; ++j) {
      const int e = eg * 4 + j;
      const float bkv = bk[h * HD + e];
      const float pkv = pk[(size_t)b * NF + h * HD + e];
      float v = acc[i][j] + bqv * pkv + bkv * pqv + 4096.f * bqv * bkv;
      Ss[d][e] = v * 0.125f;
    }
  }
  __syncthreads();

  // wave-parallel softmax over d (rows) per column e: 4 quarters x 64 cols
  const int e = tid & 63, q = tid >> 6;
  float pm = -INFINITY;
#pragma unroll
  for (int d = 0; d < 16; ++d) pm = fmaxf(pm, Ss[q * 16 + d][e]);
  red[q][e] = pm;
  __syncthreads();
  const float m = fmaxf(fmaxf(red[0][e], red[1][e]), fmaxf(red[2][e], red[3][e]));
  __syncthreads();
  float ps = 0.f;
#pragma unroll
  for (int d = 0; d < 16; ++d) {
    float ex = __expf(Ss[q * 16 + d][e] - m);
    Ss[q * 16 + d][e] = ex;
    ps += ex;
  }
  red[q][e] = ps;
  __syncthreads();
  const float inv = 1.f / (red[0][e] + red[1][e] + red[2][e] + red[3][e]);
  __syncthreads();
  float bacc = 0.f;
#pragma unroll
  for (int d = 0; d < 16; ++d) {
    const int dd = q * 16 + d;
    const float a = Ss[dd][e] * inv;
    Amat[(size_t)hb * 4096 + dd * 64 + e] = a;
    bacc = fmaf(bv[h * HD + dd], a, bacc);
  }
  red[q][e] = bacc;
  __syncthreads();
  if (tid < 64)
    bvA[(size_t)hb * HD + tid] = red[0][tid] + red[1][tid] + red[2][tid] + red[3][tid];
}

// ---------------------------------------------------------------------------
// WvA^T[b][n=h*64+e][f] (bf16 hi only) = sum_d Wv_all[f][h*64+d] * A[hb][d][e]
// ---------------------------------------------------------------------------
__global__ __launch_bounds__(256) void wva_kernel(
    const float* __restrict__ Wv_all, const float* __restrict__ Amat,
    __bf16* __restrict__ WvAt_h) {
  const int hb = blockIdx.y, h = hb >> 5, b = hb & 31;
  const int f0 = blockIdx.x * 128;
  __shared__ float Ws[128][65];
  __shared__ float As[64][65];
  const int tid = threadIdx.x;

#pragma unroll
  for (int q = 0; q < 4; ++q) {
    const int idx = q * 256 + tid;
    const int d = idx >> 4, ee = (idx & 15) * 4;
    *(float4*)&As[d][ee] = *(const float4*)&Amat[(size_t)hb * 4096 + d * 64 + ee];
  }
#pragma unroll
  for (int q = 0; q < 8; ++q) {
    const int idx = q * 256 + tid;
    const int fi = idx >> 4, dd = (idx & 15) * 4;
    *(float4*)&Ws[fi][dd] = *(const float4*)&Wv_all[(size_t)(f0 + fi) * NF + h * HD + dd];
  }
  __syncthreads();

  const int fg = tid >> 4, eg = tid & 15;
  float acc[8][4];
#pragma unroll
  for (int i = 0; i < 8; ++i)
#pragma unroll
    for (int j = 0; j < 4; ++j) acc[i][j] = 0.f;
#pragma unroll 8
  for (int d = 0; d < 64; ++d) {
    float4 av = *(float4*)&As[d][eg * 4];
    float a_[4] = {av.x, av.y, av.z, av.w};
#pragma unroll
    for (int i = 0; i < 8; ++i) {
      const float w = Ws[fg * 8 + i][d];
#pragma unroll
      for (int j = 0; j < 4; ++j) acc[i][j] = fmaf(w, a_[j], acc[i][j]);
    }
  }

  // transpose via LDS (reuse Ws as [64][130]) then coalesced bf16 store
  __syncthreads();
  float* Ts = &Ws[0][0];
#pragma unroll
  for (int i = 0; i < 8; ++i)
#pragma unroll
    for (int j = 0; j < 4; ++j)
      Ts[(eg * 4 + j) * 130 + fg * 8 + i] = acc[i][j];
  __syncthreads();

  const int e = tid >> 2, fs = (tid & 3) * 32;
  size_t orow = ((size_t)b * 512 + h * 64 + e) * 512 + f0 + fs;
#pragma unroll
  for (int c = 0; c < 4; ++c) {
    bf16x8 vh;
#pragma unroll
    for (int j = 0; j < 8; ++j)
      vh[j] = (__bf16)Ts[e * 130 + fs + c * 8 + j];
    *(bf16x8*)&WvAt_h[orow + c * 8] = vh;
  }
}

// ---------------------------------------------------------------------------
// kernel_launch
// ---------------------------------------------------------------------------
extern "C" void kernel_launch(void* const* d_in, const int* in_sizes, int n_in,
                              void* d_out, int out_size, void* d_ws, size_t ws_size,
                              hipStream_t stream) {
  const float* x  = (const float*)d_in[0];
  const float* Wq = (const float*)d_in[1];
  const float* bq = (const float*)d_in[2];
  const float* Wk = (const float*)d_in[3];
  const float* bk = (const float*)d_in[4];
  const float* Wv = (const float*)d_in[5];
  const float* bv = (const float*)d_in[6];
  const float* Wo = (const float*)d_in[7];
  const float* bo = (const float*)d_in[8];
  float* out = (float*)d_out;
  (void)in_sizes; (void)n_in; (void)out_size; (void)ws_size;

  // workspace layout (float units), total ~287 MiB (peak 362 proven in r5)
  float* w = (float*)d_ws;
  size_t off = 0;
  float* Wq_all = w + off; off += 262144;
  float* Wk_all = w + off; off += 262144;
  float* Wv_all = w + off; off += 262144;
  float* s_part = w + off; off += (size_t)32 * 64 * 512;    // 4 MiB
  float* pq     = w + off; off += 16384;
  float* pk     = w + off; off += 16384;
  float* U      = w + off; off += (size_t)32 * 262144;      // 32 MiB
  float* Amat   = w + off; off += 1048576;                  // 4 MiB
  float* bvA    = w + off; off += 16384;
  float* Gp     = w + off; off += (size_t)4 * 32 * 10 * 16384;  // 80 MiB
  __bf16* Wkt_h = (__bf16*)(w + off); off += 131072;        // 512x512 bf16
  __bf16* Wkt_l = (__bf16*)(w + off); off += 131072;
  __bf16* Wot_h = (__bf16*)(w + off); off += 131072;
  __bf16* Gh    = (__bf16*)(w + off); off += (size_t)32 * 131072;   // 16 MiB
  __bf16* Gl    = (__bf16*)(w + off); off += (size_t)32 * 131072;
  __bf16* WvAt_h= (__bf16*)(w + off); off += (size_t)32 * 131072;
  __bf16* Hh    = (__bf16*)(w + off); off += (size_t)131072 * 256;  // 128 MiB

  // 1. pack weights
  pack3_kernel<<<1024, 256, 0, stream>>>(Wq, Wk, Wv, Wo, Wq_all, Wk_all, Wv_all,
                                         Wkt_h, Wkt_l, Wot_h);
  // 2. column sums + bias-correction vectors
  colsum_kernel<<<dim3(BATCH, 64), 256, 0, stream>>>(x, s_part);
  pqk_kernel<<<BATCH, 256, 0, stream>>>(s_part, Wq_all, Wk_all, pq, pk);
  // 3. Gram partials (3-term, SYM upper-tri, split-K x4 -> 1280 blocks)
  mfma_nt<2, 2, 4, true><<<dim3(10, 4, BATCH), 256, 0, stream>>>(
      x, nullptr, (long long)SEQ * NF, NF,
      x, nullptr, (long long)SEQ * NF, NF,
      nullptr, Gp, nullptr, 0, 1024);
  // 3b. reduce partials -> Gh/Gl (both triangles)
  greduce_kernel<<<dim3(10, BATCH), 256, 0, stream>>>(Gp, Gh, Gl);
  // 4. U[b] = G[b] @ Wk_all  (3-term, bf16 pairs)
  mfma_nt<0, 0, 0><<<dim3(4, 4, BATCH), 256, 0, stream>>>(
      Gh, Gl, 262144, NF,
      Wkt_h, Wkt_l, 0, NF,
      nullptr, U, nullptr, 262144, NF);
  // 5. scores + softmax -> A, bvA
  score_softmax_kernel<<<256, 256, 0, stream>>>(Wq_all, U, pq, pk, bq, bk, bv,
                                                Amat, bvA);
  // 6. WvA^T (bf16 hi only)
  wva_kernel<<<dim3(4, 256), 256, 0, stream>>>(Wv_all, Amat, WvAt_h);
  // 7. heads: x[b] @ WvAt[b]^T + bvA -> [h][b][l][e] bf16 (1-term pure bf16)
  mfma_nt<4, 3, 3><<<dim3(4, 32, BATCH), 256, 0, stream>>>(
      x, nullptr, (long long)SEQ * NF, NF,
      WvAt_h, nullptr, 262144, NF,
      bvA, Hh, nullptr, 0, NF);
  // 8. out = Hview @ Wo + bo  (1-term pure bf16)
  mfma_nt<3, 3, 1><<<dim3(4, 1024, 1), 256, 0, stream>>>(
      Hh, nullptr, 0, NF,
      Wot_h, nullptr, 0, NF,
      bo, out, nullptr, 0, NF);
}